// Round 1
// baseline (1622.667 us; speedup 1.0000x reference)
//
#include <hip/hip_runtime.h>
#include <hip/hip_bf16.h>
#include <math.h>

#define D_MODEL 1024
#define N_HEADS 16
#define D_HEAD  64
#define SEQ     2048
#define NBATCH  2
#define NROWS   (NBATCH * SEQ)      // 4096

// ---------------------------------------------------------------------------
// GEMM: C[M,N] = A[M,K] @ B[K,N] + bias[N]   (fp32, 128x128x16 tile, 8x8/thread)
// ---------------------------------------------------------------------------
#define GBM 128
#define GBN 128
#define GBK 16

__global__ __launch_bounds__(256) void gemm_bias_kernel(
    const float* __restrict__ A, const float* __restrict__ B,
    const float* __restrict__ bias, float* __restrict__ C,
    int M, int N, int K)
{
    __shared__ float As[GBK][GBM + 4];   // stored transposed: As[k][m]
    __shared__ float Bs[GBK][GBN + 4];   // Bs[k][n]

    const int tid = threadIdx.x;
    const int tx = tid & 15;             // n-direction, 0..15
    const int ty = tid >> 4;             // m-direction, 0..15
    const int nbn = N / GBN;
    const int bm = (blockIdx.x / nbn) * GBM;
    const int bn = (blockIdx.x % nbn) * GBM == 0 ? (blockIdx.x % nbn) * GBN : (blockIdx.x % nbn) * GBN;

    // A tile loader: 128 rows x 16 k; thread loads 8 floats (2 float4)
    const int arow  = tid >> 1;          // 0..127
    const int akcol = (tid & 1) * 8;     // 0 or 8
    // B tile loader: 16 rows x 128 cols; thread loads 8 floats (2 float4)
    const int brow = tid >> 4;           // 0..15
    const int bcol = (tid & 15) * 8;     // 0..120

    const float* Aptr = A + (size_t)(bm + arow) * K + akcol;
    const float* Bptr = B + (size_t)brow * N + bn + bcol;

    float acc[8][8];
#pragma unroll
    for (int i = 0; i < 8; ++i)
#pragma unroll
        for (int j = 0; j < 8; ++j) acc[i][j] = 0.f;

    for (int k0 = 0; k0 < K; k0 += GBK) {
        float4 a0 = *(const float4*)(Aptr + k0);
        float4 a1 = *(const float4*)(Aptr + k0 + 4);
        float4 b0 = *(const float4*)(Bptr + (size_t)k0 * N);
        float4 b1 = *(const float4*)(Bptr + (size_t)k0 * N + 4);

        __syncthreads();   // previous iteration's LDS reads complete
        As[akcol + 0][arow] = a0.x;
        As[akcol + 1][arow] = a0.y;
        As[akcol + 2][arow] = a0.z;
        As[akcol + 3][arow] = a0.w;
        As[akcol + 4][arow] = a1.x;
        As[akcol + 5][arow] = a1.y;
        As[akcol + 6][arow] = a1.z;
        As[akcol + 7][arow] = a1.w;
        *(float4*)&Bs[brow][bcol]     = b0;
        *(float4*)&Bs[brow][bcol + 4] = b1;
        __syncthreads();

#pragma unroll
        for (int k = 0; k < GBK; ++k) {
            float a[8], b[8];
            *(float4*)&a[0] = *(const float4*)&As[k][ty * 8];
            *(float4*)&a[4] = *(const float4*)&As[k][ty * 8 + 4];
            *(float4*)&b[0] = *(const float4*)&Bs[k][tx * 8];
            *(float4*)&b[4] = *(const float4*)&Bs[k][tx * 8 + 4];
#pragma unroll
            for (int i = 0; i < 8; ++i)
#pragma unroll
                for (int j = 0; j < 8; ++j)
                    acc[i][j] = fmaf(a[i], b[j], acc[i][j]);
        }
    }

    // epilogue: add bias, store
    float bs[8];
#pragma unroll
    for (int j = 0; j < 8; ++j) bs[j] = bias[bn + tx * 8 + j];

#pragma unroll
    for (int i = 0; i < 8; ++i) {
        const int row = bm + ty * 8 + i;
        float* Crow = C + (size_t)row * N + bn + tx * 8;
        float4 o0, o1;
        o0.x = acc[i][0] + bs[0];
        o0.y = acc[i][1] + bs[1];
        o0.z = acc[i][2] + bs[2];
        o0.w = acc[i][3] + bs[3];
        o1.x = acc[i][4] + bs[4];
        o1.y = acc[i][5] + bs[5];
        o1.z = acc[i][6] + bs[6];
        o1.w = acc[i][7] + bs[7];
        *(float4*)(Crow)     = o0;
        *(float4*)(Crow + 4) = o1;
    }
}

// ---------------------------------------------------------------------------
// Flash attention (fp32). qkv: [4096, 3072] rows = b*2048+t,
// cols: Q at h*64, K at 1024+h*64, V at 2048+h*64.
// One block: one (b,h) and a 64-row q tile; loops over k in chunks of 32.
// 256 threads: thread = (r, g), r = q-row 0..63, g = 0..3 (16 d-dims each).
// ---------------------------------------------------------------------------
#define TQ 64
#define TK 32

__global__ __launch_bounds__(256) void attn_kernel(
    const float* __restrict__ qkv, float* __restrict__ aout)
{
    __shared__ float Qs[TQ][D_HEAD + 4];
    __shared__ float Ks[TK][D_HEAD + 4];
    __shared__ float Vs[TK][D_HEAD + 4];
    __shared__ float Ps[TQ][TK + 4];

    const int tid = threadIdx.x;
    const int bh = blockIdx.x;            // 0..31 : b*16 + h
    const int qt = blockIdx.y;            // 0..31
    const int b = bh >> 4;
    const int h = bh & 15;
    const int row0 = b * SEQ + qt * TQ;   // first global q-row of this tile
    const int krow0 = b * SEQ;

    // ---- load Q tile: 64x64 floats, 16 per thread ----
    {
        const int i  = tid >> 2;
        const int d0 = (tid & 3) * 16;
        const float* src = qkv + (size_t)(row0 + i) * (3 * D_MODEL) + h * D_HEAD + d0;
        float4 q0 = *(const float4*)(src);
        float4 q1 = *(const float4*)(src + 4);
        float4 q2 = *(const float4*)(src + 8);
        float4 q3 = *(const float4*)(src + 12);
        *(float4*)&Qs[i][d0]      = q0;
        *(float4*)&Qs[i][d0 + 4]  = q1;
        *(float4*)&Qs[i][d0 + 8]  = q2;
        *(float4*)&Qs[i][d0 + 12] = q3;
    }

    const int r = tid >> 2;               // q row within tile
    const int g = tid & 3;                // group: cols g*8..g*8+7 of scores, dims g*16.. of O

    float O[16];
#pragma unroll
    for (int j = 0; j < 16; ++j) O[j] = 0.f;
    float mrow = -1e30f;
    float lrow = 0.f;

    // K/V chunk loader indices: 32x64 floats, 8 per thread
    const int ki = tid >> 3;              // 0..31
    const int kd = (tid & 7) * 8;         // 0..56

    for (int kc = 0; kc < SEQ; kc += TK) {
        const float* ksrc = qkv + (size_t)(krow0 + kc + ki) * (3 * D_MODEL) + D_MODEL     + h * D_HEAD + kd;
        const float* vsrc = qkv + (size_t)(krow0 + kc + ki) * (3 * D_MODEL) + 2 * D_MODEL + h * D_HEAD + kd;
        float4 k0 = *(const float4*)(ksrc);
        float4 k1 = *(const float4*)(ksrc + 4);
        float4 v0 = *(const float4*)(vsrc);
        float4 v1 = *(const float4*)(vsrc + 4);

        __syncthreads();   // previous chunk's Ks/Vs reads complete
        *(float4*)&Ks[ki][kd]     = k0;
        *(float4*)&Ks[ki][kd + 4] = k1;
        *(float4*)&Vs[ki][kd]     = v0;
        *(float4*)&Vs[ki][kd + 4] = v1;
        __syncthreads();

        // ---- scores: thread computes s[0..7] for cols c = g*8+cc ----
        float s[8];
#pragma unroll
        for (int cc = 0; cc < 8; ++cc) s[cc] = 0.f;
        for (int dd = 0; dd < D_HEAD; dd += 4) {
            const float q0 = Qs[r][dd];
            const float q1 = Qs[r][dd + 1];
            const float q2 = Qs[r][dd + 2];
            const float q3 = Qs[r][dd + 3];
#pragma unroll
            for (int cc = 0; cc < 8; ++cc) {
                const int c = g * 8 + cc;
                s[cc] = fmaf(q0, Ks[c][dd],     s[cc]);
                s[cc] = fmaf(q1, Ks[c][dd + 1], s[cc]);
                s[cc] = fmaf(q2, Ks[c][dd + 2], s[cc]);
                s[cc] = fmaf(q3, Ks[c][dd + 3], s[cc]);
            }
        }

        float smax = -1e30f;
#pragma unroll
        for (int cc = 0; cc < 8; ++cc) {
            s[cc] *= 0.125f;              // 1/sqrt(64)
            smax = fmaxf(smax, s[cc]);
        }
        // reduce max over the 4 lanes of this q-row (consecutive lanes)
        smax = fmaxf(smax, __shfl_xor(smax, 1));
        smax = fmaxf(smax, __shfl_xor(smax, 2));

        const float mnew = fmaxf(mrow, smax);
        const float scale = __expf(mrow - mnew);
        float psum = 0.f;
        float p[8];
#pragma unroll
        for (int cc = 0; cc < 8; ++cc) {
            p[cc] = __expf(s[cc] - mnew);
            psum += p[cc];
        }
        psum += __shfl_xor(psum, 1);
        psum += __shfl_xor(psum, 2);
        lrow = lrow * scale + psum;
        mrow = mnew;
#pragma unroll
        for (int j = 0; j < 16; ++j) O[j] *= scale;

#pragma unroll
        for (int cc = 0; cc < 8; ++cc) Ps[r][g * 8 + cc] = p[cc];
        __syncthreads();   // P visible to all 4 groups of each row

        // ---- O += P @ V  (thread: dims g*16..g*16+15 of row r) ----
        for (int k = 0; k < TK; ++k) {
            const float pv = Ps[r][k];
            const float4 w0 = *(const float4*)&Vs[k][g * 16];
            const float4 w1 = *(const float4*)&Vs[k][g * 16 + 4];
            const float4 w2 = *(const float4*)&Vs[k][g * 16 + 8];
            const float4 w3 = *(const float4*)&Vs[k][g * 16 + 12];
            O[0]  = fmaf(pv, w0.x, O[0]);
            O[1]  = fmaf(pv, w0.y, O[1]);
            O[2]  = fmaf(pv, w0.z, O[2]);
            O[3]  = fmaf(pv, w0.w, O[3]);
            O[4]  = fmaf(pv, w1.x, O[4]);
            O[5]  = fmaf(pv, w1.y, O[5]);
            O[6]  = fmaf(pv, w1.z, O[6]);
            O[7]  = fmaf(pv, w1.w, O[7]);
            O[8]  = fmaf(pv, w2.x, O[8]);
            O[9]  = fmaf(pv, w2.y, O[9]);
            O[10] = fmaf(pv, w2.z, O[10]);
            O[11] = fmaf(pv, w2.w, O[11]);
            O[12] = fmaf(pv, w3.x, O[12]);
            O[13] = fmaf(pv, w3.y, O[13]);
            O[14] = fmaf(pv, w3.z, O[14]);
            O[15] = fmaf(pv, w3.w, O[15]);
        }
    }

    // ---- finalize: O /= l, write out ----
    const float inv_l = 1.0f / lrow;
    float* dst = aout + (size_t)(row0 + r) * D_MODEL + h * D_HEAD + g * 16;
    float4 o0, o1, o2, o3;
    o0.x = O[0] * inv_l;  o0.y = O[1] * inv_l;  o0.z = O[2] * inv_l;  o0.w = O[3] * inv_l;
    o1.x = O[4] * inv_l;  o1.y = O[5] * inv_l;  o1.z = O[6] * inv_l;  o1.w = O[7] * inv_l;
    o2.x = O[8] * inv_l;  o2.y = O[9] * inv_l;  o2.z = O[10] * inv_l; o2.w = O[11] * inv_l;
    o3.x = O[12] * inv_l; o3.y = O[13] * inv_l; o3.z = O[14] * inv_l; o3.w = O[15] * inv_l;
    *(float4*)(dst)      = o0;
    *(float4*)(dst + 4)  = o1;
    *(float4*)(dst + 8)  = o2;
    *(float4*)(dst + 12) = o3;
}

// ---------------------------------------------------------------------------
extern "C" void kernel_launch(void* const* d_in, const int* in_sizes, int n_in,
                              void* d_out, int out_size, void* d_ws, size_t ws_size,
                              hipStream_t stream) {
    (void)in_sizes; (void)n_in; (void)out_size; (void)ws_size;

    const float* x     = (const float*)d_in[0];   // [4096, 1024]
    const float* w_qkv = (const float*)d_in[1];   // [1024, 3072]
    const float* b_qkv = (const float*)d_in[2];   // [3072]
    const float* w_out = (const float*)d_in[3];   // [1024, 1024]
    const float* b_out = (const float*)d_in[4];   // [1024]
    float* out = (float*)d_out;                   // [4096, 1024]

    float* qkv  = (float*)d_ws;                           // 4096*3072 fp32 = 50.3 MB
    float* attn = qkv + (size_t)NROWS * 3 * D_MODEL;      // 4096*1024 fp32 = 16.8 MB

    // 1) QKV projection
    gemm_bias_kernel<<<dim3((NROWS / GBM) * (3 * D_MODEL / GBN)), 256, 0, stream>>>(
        x, w_qkv, b_qkv, qkv, NROWS, 3 * D_MODEL, D_MODEL);

    // 2) flash attention
    attn_kernel<<<dim3(NBATCH * N_HEADS, SEQ / TQ), 256, 0, stream>>>(qkv, attn);

    // 3) output projection
    gemm_bias_kernel<<<dim3((NROWS / GBM) * (D_MODEL / GBN)), 256, 0, stream>>>(
        attn, w_out, b_out, out, NROWS, D_MODEL, D_MODEL);
}

// Round 2
// 584.564 us; speedup vs baseline: 2.7759x; 2.7759x over previous
//
#include <hip/hip_runtime.h>
#include <hip/hip_bf16.h>
#include <math.h>

#define D_MODEL 1024
#define N_HEADS 16
#define D_HEAD  64
#define SEQ     2048
#define NBATCH  2
#define NROWS   (NBATCH * SEQ)      // 4096

typedef __attribute__((ext_vector_type(8))) short short8v;   // 8 bf16 (4 VGPRs)
typedef __attribute__((ext_vector_type(4))) float f32x4;

__device__ __forceinline__ unsigned short f2bf(float x) {
    unsigned int u = __float_as_uint(x);
    return (unsigned short)((u + 0x7FFFu + ((u >> 16) & 1u)) >> 16);   // RNE
}

// ---------------------------------------------------------------------------
// GEMM: C[M,N] = A[M,K] @ B[K,N] + bias[N]   (fp32, 128x128x16 tile, 8x8/thread)
// ---------------------------------------------------------------------------
#define GBM 128
#define GBN 128
#define GBK 16

__global__ __launch_bounds__(256) void gemm_bias_kernel(
    const float* __restrict__ A, const float* __restrict__ B,
    const float* __restrict__ bias, float* __restrict__ C,
    int M, int N, int K)
{
    __shared__ float As[GBK][GBM + 4];   // stored transposed: As[k][m]
    __shared__ float Bs[GBK][GBN + 4];   // Bs[k][n]

    const int tid = threadIdx.x;
    const int tx = tid & 15;
    const int ty = tid >> 4;
    const int nbn = N / GBN;
    const int bm = (blockIdx.x / nbn) * GBM;
    const int bn = (blockIdx.x % nbn) * GBN;

    const int arow  = tid >> 1;
    const int akcol = (tid & 1) * 8;
    const int brow = tid >> 4;
    const int bcol = (tid & 15) * 8;

    const float* Aptr = A + (size_t)(bm + arow) * K + akcol;
    const float* Bptr = B + (size_t)brow * N + bn + bcol;

    float acc[8][8];
#pragma unroll
    for (int i = 0; i < 8; ++i)
#pragma unroll
        for (int j = 0; j < 8; ++j) acc[i][j] = 0.f;

    for (int k0 = 0; k0 < K; k0 += GBK) {
        float4 a0 = *(const float4*)(Aptr + k0);
        float4 a1 = *(const float4*)(Aptr + k0 + 4);
        float4 b0 = *(const float4*)(Bptr + (size_t)k0 * N);
        float4 b1 = *(const float4*)(Bptr + (size_t)k0 * N + 4);

        __syncthreads();
        As[akcol + 0][arow] = a0.x;
        As[akcol + 1][arow] = a0.y;
        As[akcol + 2][arow] = a0.z;
        As[akcol + 3][arow] = a0.w;
        As[akcol + 4][arow] = a1.x;
        As[akcol + 5][arow] = a1.y;
        As[akcol + 6][arow] = a1.z;
        As[akcol + 7][arow] = a1.w;
        *(float4*)&Bs[brow][bcol]     = b0;
        *(float4*)&Bs[brow][bcol + 4] = b1;
        __syncthreads();

#pragma unroll
        for (int k = 0; k < GBK; ++k) {
            float a[8], b[8];
            *(float4*)&a[0] = *(const float4*)&As[k][ty * 8];
            *(float4*)&a[4] = *(const float4*)&As[k][ty * 8 + 4];
            *(float4*)&b[0] = *(const float4*)&Bs[k][tx * 8];
            *(float4*)&b[4] = *(const float4*)&Bs[k][tx * 8 + 4];
#pragma unroll
            for (int i = 0; i < 8; ++i)
#pragma unroll
                for (int j = 0; j < 8; ++j)
                    acc[i][j] = fmaf(a[i], b[j], acc[i][j]);
        }
    }

    float bs[8];
#pragma unroll
    for (int j = 0; j < 8; ++j) bs[j] = bias[bn + tx * 8 + j];

#pragma unroll
    for (int i = 0; i < 8; ++i) {
        const int row = bm + ty * 8 + i;
        float* Crow = C + (size_t)row * N + bn + tx * 8;
        float4 o0, o1;
        o0.x = acc[i][0] + bs[0];
        o0.y = acc[i][1] + bs[1];
        o0.z = acc[i][2] + bs[2];
        o0.w = acc[i][3] + bs[3];
        o1.x = acc[i][4] + bs[4];
        o1.y = acc[i][5] + bs[5];
        o1.z = acc[i][6] + bs[6];
        o1.w = acc[i][7] + bs[7];
        *(float4*)(Crow)     = o0;
        *(float4*)(Crow + 4) = o1;
    }
}

// ---------------------------------------------------------------------------
// MFMA flash attention (bf16 inputs, fp32 accum).
// Block: 256 threads = 4 waves. QBLK=64 (16 q-rows/wave), KBLK=64.
// qkv fp32 [4096][3072]: Q at h*64, K at 1024+h*64, V at 2048+h*64.
// mfma_f32_16x16x32_bf16: A row=lane&15, k=(lane>>4)*8+j (symmetric for B);
// C/D: col=lane&15, row=(lane>>4)*4+reg.
// ---------------------------------------------------------------------------
#define KBLK 64
#define PSTRIDE 72            // bf16 elements; 144 B row stride (16B-aligned, 2-way banks)

__global__ __launch_bounds__(256) void attn_mfma_kernel(
    const float* __restrict__ qkv, float* __restrict__ aout)
{
    __shared__ __align__(16) unsigned short Ks[KBLK][PSTRIDE];      // [key][dim]
    __shared__ __align__(16) unsigned short Vt[D_HEAD][PSTRIDE];    // [dim][key]
    __shared__ __align__(16) unsigned short Ps[4][16][PSTRIDE];     // per-wave [qrow][key]

    const int tid  = threadIdx.x;
    const int wave = tid >> 6;
    const int lane = tid & 63;
    const int col  = lane & 15;
    const int q4   = lane >> 4;

    const int bh = blockIdx.x;            // b*16 + h
    const int qt = blockIdx.y;            // 0..31
    const int b = bh >> 4;
    const int h = bh & 15;
    const int qrow0 = b * SEQ + qt * 64 + wave * 16;   // this wave's first q row (global)
    const int krow0 = b * SEQ;

    // ---- Q fragments in registers (A-operand), pre-scaled by 1/sqrt(64) ----
    short8v qfrag[2];
    {
        const float* qsrc = qkv + (size_t)(qrow0 + col) * (3 * D_MODEL) + h * D_HEAD;
#pragma unroll
        for (int ks = 0; ks < 2; ++ks) {
            float4 f0 = *(const float4*)(qsrc + ks * 32 + q4 * 8);
            float4 f1 = *(const float4*)(qsrc + ks * 32 + q4 * 8 + 4);
            unsigned short u[8];
            u[0] = f2bf(f0.x * 0.125f); u[1] = f2bf(f0.y * 0.125f);
            u[2] = f2bf(f0.z * 0.125f); u[3] = f2bf(f0.w * 0.125f);
            u[4] = f2bf(f1.x * 0.125f); u[5] = f2bf(f1.y * 0.125f);
            u[6] = f2bf(f1.z * 0.125f); u[7] = f2bf(f1.w * 0.125f);
            unsigned short* p = (unsigned short*)&qfrag[ks];
#pragma unroll
            for (int j = 0; j < 8; ++j) p[j] = u[j];
        }
    }

    // staging indices
    const int kkey = tid >> 2;            // 0..63
    const int kd16 = (tid & 3) * 16;      // 0,16,32,48
    const int vd4  = (tid & 15) * 4;      // dim block 0..60
    const int vkey0 = (tid >> 4) * 4;     // key block 0..60

    f32x4 o[4];
#pragma unroll
    for (int nt = 0; nt < 4; ++nt) o[nt] = (f32x4){0.f, 0.f, 0.f, 0.f};
    float m[4], l[4];
#pragma unroll
    for (int r = 0; r < 4; ++r) { m[r] = -1e30f; l[r] = 0.f; }

    for (int kc = 0; kc < SEQ; kc += KBLK) {
        // ---- global loads (before barrier, overlap w/ prior compute) ----
        const float* ksrc = qkv + (size_t)(krow0 + kc + kkey) * (3 * D_MODEL) + D_MODEL + h * D_HEAD + kd16;
        float4 ka = *(const float4*)(ksrc);
        float4 kb = *(const float4*)(ksrc + 4);
        float4 kc4 = *(const float4*)(ksrc + 8);
        float4 kd4 = *(const float4*)(ksrc + 12);
        float4 vv[4];
#pragma unroll
        for (int i = 0; i < 4; ++i) {
            const float* vsrc = qkv + (size_t)(krow0 + kc + vkey0 + i) * (3 * D_MODEL) + 2 * D_MODEL + h * D_HEAD + vd4;
            vv[i] = *(const float4*)(vsrc);
        }

        __syncthreads();   // previous chunk's LDS reads done

        // K row-major
        {
            unsigned short u[16];
            u[0]=f2bf(ka.x); u[1]=f2bf(ka.y); u[2]=f2bf(ka.z); u[3]=f2bf(ka.w);
            u[4]=f2bf(kb.x); u[5]=f2bf(kb.y); u[6]=f2bf(kb.z); u[7]=f2bf(kb.w);
            u[8]=f2bf(kc4.x); u[9]=f2bf(kc4.y); u[10]=f2bf(kc4.z); u[11]=f2bf(kc4.w);
            u[12]=f2bf(kd4.x); u[13]=f2bf(kd4.y); u[14]=f2bf(kd4.z); u[15]=f2bf(kd4.w);
            unsigned short* dst = &Ks[kkey][kd16];
#pragma unroll
            for (int half = 0; half < 2; ++half) {
                short8v v;
                unsigned short* p = (unsigned short*)&v;
#pragma unroll
                for (int j = 0; j < 8; ++j) p[j] = u[half * 8 + j];
                *(short8v*)(dst + half * 8) = v;
            }
        }
        // V transposed: Vt[dim][key]; 4x4 in-register transpose, b64 writes
        {
            const float* vf = (const float*)&vv[0];
#pragma unroll
            for (int j = 0; j < 4; ++j) {
                ushort4 w;
                w.x = f2bf(((const float*)&vv[0])[j]);
                w.y = f2bf(((const float*)&vv[1])[j]);
                w.z = f2bf(((const float*)&vv[2])[j]);
                w.w = f2bf(((const float*)&vv[3])[j]);
                *(ushort4*)(&Vt[vd4 + j][vkey0]) = w;
            }
            (void)vf;
        }
        __syncthreads();

        // ---- S = Q K^T : 4 key-tiles x 2 k-steps ----
        f32x4 s[4];
#pragma unroll
        for (int nt = 0; nt < 4; ++nt) {
            s[nt] = (f32x4){0.f, 0.f, 0.f, 0.f};
#pragma unroll
            for (int ks = 0; ks < 2; ++ks) {
                short8v kf = *(const short8v*)&Ks[nt * 16 + col][ks * 32 + q4 * 8];
                s[nt] = __builtin_amdgcn_mfma_f32_16x16x32_bf16(qfrag[ks], kf, s[nt], 0, 0, 0);
            }
        }

        // ---- online softmax (rows = (q4)*4+r, cols = keys across lanes) ----
        float mx[4];
#pragma unroll
        for (int r = 0; r < 4; ++r) {
            mx[r] = fmaxf(fmaxf(s[0][r], s[1][r]), fmaxf(s[2][r], s[3][r]));
            mx[r] = fmaxf(mx[r], __shfl_xor(mx[r], 1));
            mx[r] = fmaxf(mx[r], __shfl_xor(mx[r], 2));
            mx[r] = fmaxf(mx[r], __shfl_xor(mx[r], 4));
            mx[r] = fmaxf(mx[r], __shfl_xor(mx[r], 8));
        }
        float cf[4], rs[4];
#pragma unroll
        for (int r = 0; r < 4; ++r) {
            const float mnew = fmaxf(m[r], mx[r]);
            cf[r] = __expf(m[r] - mnew);
            m[r] = mnew;
            rs[r] = 0.f;
        }
#pragma unroll
        for (int nt = 0; nt < 4; ++nt)
#pragma unroll
            for (int r = 0; r < 4; ++r) {
                const float p = __expf(s[nt][r] - m[r]);
                s[nt][r] = p;
                rs[r] += p;
            }
#pragma unroll
        for (int r = 0; r < 4; ++r) {
            rs[r] += __shfl_xor(rs[r], 1);
            rs[r] += __shfl_xor(rs[r], 2);
            rs[r] += __shfl_xor(rs[r], 4);
            rs[r] += __shfl_xor(rs[r], 8);
            l[r] = l[r] * cf[r] + rs[r];
        }
        // rescale O
#pragma unroll
        for (int nt = 0; nt < 4; ++nt)
#pragma unroll
            for (int r = 0; r < 4; ++r) o[nt][r] *= cf[r];

        // ---- P -> LDS (bf16), per-wave buffer, same-wave round trip ----
#pragma unroll
        for (int nt = 0; nt < 4; ++nt)
#pragma unroll
            for (int r = 0; r < 4; ++r)
                Ps[wave][q4 * 4 + r][nt * 16 + col] = f2bf(s[nt][r]);

        // ---- O += P V : A = P rows, B = Vt rows ----
        short8v pf0 = *(const short8v*)&Ps[wave][col][q4 * 8];
        short8v pf1 = *(const short8v*)&Ps[wave][col][32 + q4 * 8];
#pragma unroll
        for (int nt = 0; nt < 4; ++nt) {
            short8v vf0 = *(const short8v*)&Vt[nt * 16 + col][q4 * 8];
            short8v vf1 = *(const short8v*)&Vt[nt * 16 + col][32 + q4 * 8];
            o[nt] = __builtin_amdgcn_mfma_f32_16x16x32_bf16(pf0, vf0, o[nt], 0, 0, 0);
            o[nt] = __builtin_amdgcn_mfma_f32_16x16x32_bf16(pf1, vf1, o[nt], 0, 0, 0);
        }
    }

    // ---- finalize ----
#pragma unroll
    for (int r = 0; r < 4; ++r) {
        const float il = 1.0f / l[r];
        float* dst = aout + (size_t)(qrow0 + q4 * 4 + r) * D_MODEL + h * D_HEAD;
#pragma unroll
        for (int nt = 0; nt < 4; ++nt)
            dst[nt * 16 + col] = o[nt][r] * il;
    }
}

// ---------------------------------------------------------------------------
extern "C" void kernel_launch(void* const* d_in, const int* in_sizes, int n_in,
                              void* d_out, int out_size, void* d_ws, size_t ws_size,
                              hipStream_t stream) {
    (void)in_sizes; (void)n_in; (void)out_size; (void)ws_size;

    const float* x     = (const float*)d_in[0];
    const float* w_qkv = (const float*)d_in[1];
    const float* b_qkv = (const float*)d_in[2];
    const float* w_out = (const float*)d_in[3];
    const float* b_out = (const float*)d_in[4];
    float* out = (float*)d_out;

    float* qkv  = (float*)d_ws;                           // 4096*3072 fp32
    float* attn = qkv + (size_t)NROWS * 3 * D_MODEL;      // 4096*1024 fp32

    gemm_bias_kernel<<<dim3((NROWS / GBM) * (3 * D_MODEL / GBN)), 256, 0, stream>>>(
        x, w_qkv, b_qkv, qkv, NROWS, 3 * D_MODEL, D_MODEL);

    attn_mfma_kernel<<<dim3(NBATCH * N_HEADS, SEQ / 64), 256, 0, stream>>>(qkv, attn);

    gemm_bias_kernel<<<dim3((NROWS / GBM) * (D_MODEL / GBN)), 256, 0, stream>>>(
        attn, w_out, b_out, out, NROWS, D_MODEL, D_MODEL);
}

// Round 3
// 308.021 us; speedup vs baseline: 5.2680x; 1.8978x over previous
//
#include <hip/hip_runtime.h>
#include <hip/hip_bf16.h>
#include <math.h>

#define D_MODEL 1024
#define N_HEADS 16
#define D_HEAD  64
#define SEQ     2048
#define NBATCH  2
#define NROWS   (NBATCH * SEQ)      // 4096

typedef __attribute__((ext_vector_type(8))) short short8v;   // 8 bf16 (4 VGPRs)
typedef __attribute__((ext_vector_type(4))) float f32x4;

__device__ __forceinline__ unsigned short f2bf(float x) {
    unsigned int u = __float_as_uint(x);
    return (unsigned short)((u + 0x7FFFu + ((u >> 16) & 1u)) >> 16);   // RNE
}
__device__ __forceinline__ float bf2f(unsigned short h) {
    return __uint_as_float(((unsigned int)h) << 16);
}
// truncation split: hi = top-16-bits of fp32 (exact residual), lo = RNE(x - hi)
__device__ __forceinline__ void split_bf(float x, unsigned short& hi, unsigned short& lo) {
    unsigned int u = __float_as_uint(x);
    unsigned int ht = u & 0xFFFF0000u;
    hi = (unsigned short)(ht >> 16);
    lo = f2bf(x - __uint_as_float(ht));
}

// ---------------------------------------------------------------------------
// Weight transpose + split: W[K][N] fp32 -> Th[N][K], Tl[N][K] bf16
// ---------------------------------------------------------------------------
__global__ __launch_bounds__(256) void splitT_kernel(
    const float* __restrict__ W, unsigned short* __restrict__ Th,
    unsigned short* __restrict__ Tl, int K, int N)
{
    __shared__ float tile[64][68];
    const int tid = threadIdx.x;
    const int nbn = N >> 6;
    const int k0 = (blockIdx.x / nbn) << 6;
    const int n0 = (blockIdx.x % nbn) << 6;
    const int r  = tid >> 4;
    const int c4 = (tid & 15) * 4;

#pragma unroll
    for (int i = 0; i < 4; ++i) {
        float4 v = *(const float4*)(W + (size_t)(k0 + r + i * 16) * N + n0 + c4);
        *(float4*)&tile[r + i * 16][c4] = v;
    }
    __syncthreads();

    const int kl = (tid & 15) * 4;
#pragma unroll
    for (int i = 0; i < 4; ++i) {
        const int nl = (tid >> 4) + i * 16;
        ushort4 h4, l4;
        unsigned short h, l;
        split_bf(tile[kl + 0][nl], h, l); h4.x = h; l4.x = l;
        split_bf(tile[kl + 1][nl], h, l); h4.y = h; l4.y = l;
        split_bf(tile[kl + 2][nl], h, l); h4.z = h; l4.z = l;
        split_bf(tile[kl + 3][nl], h, l); h4.w = h; l4.w = l;
        *(ushort4*)(Th + (size_t)(n0 + nl) * K + k0 + kl) = h4;
        *(ushort4*)(Tl + (size_t)(n0 + nl) * K + k0 + kl) = l4;
    }
}

// ---------------------------------------------------------------------------
// Split-bf16 MFMA GEMM: C[M,N] = A[M,K](fp32) @ Bt[N,K](hi/lo bf16)^T + bias
// 3-term: AhBh + AlBh + AhBl. Tile 128x128xBK32, 4 waves (2x2), each 64x64.
// OUT_BF16: C stored as bf16 (for qkv); else fp32.
// ---------------------------------------------------------------------------
#define ASTRIDE 40    // bf16 elems; 80B row stride: 16B-aligned, 2-way banks (free)

template<int OUT_BF16>
__global__ __launch_bounds__(256) void gemm_split_kernel(
    const float* __restrict__ A,
    const unsigned short* __restrict__ Bth,
    const unsigned short* __restrict__ Btl,
    const float* __restrict__ bias,
    void* __restrict__ Cout, int M, int N, int K)
{
    __shared__ __align__(16) unsigned short Ah[128][ASTRIDE];
    __shared__ __align__(16) unsigned short Al[128][ASTRIDE];
    __shared__ __align__(16) unsigned short Bh[128][ASTRIDE];
    __shared__ __align__(16) unsigned short Bl[128][ASTRIDE];

    const int tid  = threadIdx.x;
    const int wave = tid >> 6;
    const int lane = tid & 63;
    const int col  = lane & 15;
    const int q4   = lane >> 4;
    const int wm   = (wave >> 1) * 64;
    const int wn   = (wave & 1) * 64;

    // XCD-aware swizzle (grid % 8 == 0 for all our launches), n-fast
    const int nwg = gridDim.x;
    const int cpx = nwg >> 3;
    const int swz = (blockIdx.x & 7) * cpx + (blockIdx.x >> 3);
    const int nbn = N / 128;
    const int bm = (swz / nbn) * 128;
    const int bn = (swz % nbn) * 128;

    // staging: row sr (0..127), k-quarter sq (0 or 16)
    const int sr = tid >> 1;
    const int sq = (tid & 1) * 16;
    const float* aptr = A + (size_t)(bm + sr) * K + sq;
    const unsigned short* bhp = Bth + (size_t)(bn + sr) * K + sq;
    const unsigned short* blp = Btl + (size_t)(bn + sr) * K + sq;

    f32x4 acc[4][4];
#pragma unroll
    for (int i = 0; i < 4; ++i)
#pragma unroll
        for (int j = 0; j < 4; ++j) acc[i][j] = (f32x4){0.f, 0.f, 0.f, 0.f};

    for (int k0 = 0; k0 < K; k0 += 32) {
        float4 a0 = *(const float4*)(aptr + k0);
        float4 a1 = *(const float4*)(aptr + k0 + 4);
        float4 a2 = *(const float4*)(aptr + k0 + 8);
        float4 a3 = *(const float4*)(aptr + k0 + 12);
        short8v b0h = *(const short8v*)(bhp + k0);
        short8v b1h = *(const short8v*)(bhp + k0 + 8);
        short8v b0l = *(const short8v*)(blp + k0);
        short8v b1l = *(const short8v*)(blp + k0 + 8);

        __syncthreads();   // previous iteration's LDS reads complete

        {
            float af[16] = {a0.x, a0.y, a0.z, a0.w, a1.x, a1.y, a1.z, a1.w,
                            a2.x, a2.y, a2.z, a2.w, a3.x, a3.y, a3.z, a3.w};
            short8v h0, h1, l0, l1;
            unsigned short* ph0 = (unsigned short*)&h0;
            unsigned short* ph1 = (unsigned short*)&h1;
            unsigned short* pl0 = (unsigned short*)&l0;
            unsigned short* pl1 = (unsigned short*)&l1;
#pragma unroll
            for (int j = 0; j < 8; ++j) {
                unsigned short h, l;
                split_bf(af[j], h, l);     ph0[j] = h; pl0[j] = l;
                split_bf(af[j + 8], h, l); ph1[j] = h; pl1[j] = l;
            }
            *(short8v*)&Ah[sr][sq]     = h0;
            *(short8v*)&Ah[sr][sq + 8] = h1;
            *(short8v*)&Al[sr][sq]     = l0;
            *(short8v*)&Al[sr][sq + 8] = l1;
            *(short8v*)&Bh[sr][sq]     = b0h;
            *(short8v*)&Bh[sr][sq + 8] = b1h;
            *(short8v*)&Bl[sr][sq]     = b0l;
            *(short8v*)&Bl[sr][sq + 8] = b1l;
        }
        __syncthreads();

        short8v ahf[4], alf[4];
#pragma unroll
        for (int mt = 0; mt < 4; ++mt) {
            ahf[mt] = *(const short8v*)&Ah[wm + mt * 16 + col][q4 * 8];
            alf[mt] = *(const short8v*)&Al[wm + mt * 16 + col][q4 * 8];
        }
#pragma unroll
        for (int nt = 0; nt < 4; ++nt) {
            short8v bhf = *(const short8v*)&Bh[wn + nt * 16 + col][q4 * 8];
            short8v blf = *(const short8v*)&Bl[wn + nt * 16 + col][q4 * 8];
#pragma unroll
            for (int mt = 0; mt < 4; ++mt) {
                acc[mt][nt] = __builtin_amdgcn_mfma_f32_16x16x32_bf16(ahf[mt], bhf, acc[mt][nt], 0, 0, 0);
                acc[mt][nt] = __builtin_amdgcn_mfma_f32_16x16x32_bf16(alf[mt], bhf, acc[mt][nt], 0, 0, 0);
                acc[mt][nt] = __builtin_amdgcn_mfma_f32_16x16x32_bf16(ahf[mt], blf, acc[mt][nt], 0, 0, 0);
            }
        }
    }

    // epilogue
    float bv[4];
#pragma unroll
    for (int nt = 0; nt < 4; ++nt) bv[nt] = bias[bn + wn + nt * 16 + col];

    if (OUT_BF16) {
        unsigned short* Cb = (unsigned short*)Cout;
#pragma unroll
        for (int mt = 0; mt < 4; ++mt)
#pragma unroll
            for (int r = 0; r < 4; ++r) {
                const int row = bm + wm + mt * 16 + q4 * 4 + r;
#pragma unroll
                for (int nt = 0; nt < 4; ++nt)
                    Cb[(size_t)row * N + bn + wn + nt * 16 + col] = f2bf(acc[mt][nt][r] + bv[nt]);
            }
    } else {
        float* Cf = (float*)Cout;
#pragma unroll
        for (int mt = 0; mt < 4; ++mt)
#pragma unroll
            for (int r = 0; r < 4; ++r) {
                const int row = bm + wm + mt * 16 + q4 * 4 + r;
#pragma unroll
                for (int nt = 0; nt < 4; ++nt)
                    Cf[(size_t)row * N + bn + wn + nt * 16 + col] = acc[mt][nt][r] + bv[nt];
            }
    }
}

// ---------------------------------------------------------------------------
// MFMA flash attention, bf16 qkv input [4096][3072], fp32 output [4096][1024].
// Scores scaled by 0.125 post-MFMA (Q unscaled in qkv).
// ---------------------------------------------------------------------------
#define KBLK 64
#define PSTRIDE 72

__global__ __launch_bounds__(256) void attn_mfma_kernel(
    const unsigned short* __restrict__ qkv, float* __restrict__ aout)
{
    __shared__ __align__(16) unsigned short Ks[KBLK][PSTRIDE];
    __shared__ __align__(16) unsigned short Vt[D_HEAD][PSTRIDE];
    __shared__ __align__(16) unsigned short Ps[4][16][PSTRIDE];

    const int tid  = threadIdx.x;
    const int wave = tid >> 6;
    const int lane = tid & 63;
    const int col  = lane & 15;
    const int q4   = lane >> 4;

    const int bh = blockIdx.x;
    const int qt = blockIdx.y;
    const int b = bh >> 4;
    const int h = bh & 15;
    const int qrow0 = b * SEQ + qt * 64 + wave * 16;
    const int krow0 = b * SEQ;

    // Q fragments directly from bf16 global
    short8v qfrag[2];
    {
        const unsigned short* qsrc = qkv + (size_t)(qrow0 + col) * (3 * D_MODEL) + h * D_HEAD;
        qfrag[0] = *(const short8v*)(qsrc + q4 * 8);
        qfrag[1] = *(const short8v*)(qsrc + 32 + q4 * 8);
    }

    const int kkey = tid >> 2;
    const int kd16 = (tid & 3) * 16;
    const int vd4  = (tid & 15) * 4;
    const int vkey0 = (tid >> 4) * 4;

    f32x4 o[4];
#pragma unroll
    for (int nt = 0; nt < 4; ++nt) o[nt] = (f32x4){0.f, 0.f, 0.f, 0.f};
    float m[4], l[4];
#pragma unroll
    for (int r = 0; r < 4; ++r) { m[r] = -1e30f; l[r] = 0.f; }

    for (int kc = 0; kc < SEQ; kc += KBLK) {
        const unsigned short* ksrc = qkv + (size_t)(krow0 + kc + kkey) * (3 * D_MODEL) + D_MODEL + h * D_HEAD + kd16;
        short8v kv0 = *(const short8v*)(ksrc);
        short8v kv1 = *(const short8v*)(ksrc + 8);
        ushort4 vr[4];
#pragma unroll
        for (int i = 0; i < 4; ++i)
            vr[i] = *(const ushort4*)(qkv + (size_t)(krow0 + kc + vkey0 + i) * (3 * D_MODEL) + 2 * D_MODEL + h * D_HEAD + vd4);

        __syncthreads();

        *(short8v*)&Ks[kkey][kd16]     = kv0;
        *(short8v*)&Ks[kkey][kd16 + 8] = kv1;
#pragma unroll
        for (int j = 0; j < 4; ++j) {
            ushort4 w;
            w.x = ((const unsigned short*)&vr[0])[j];
            w.y = ((const unsigned short*)&vr[1])[j];
            w.z = ((const unsigned short*)&vr[2])[j];
            w.w = ((const unsigned short*)&vr[3])[j];
            *(ushort4*)(&Vt[vd4 + j][vkey0]) = w;
        }
        __syncthreads();

        // S = Q K^T
        f32x4 s[4];
#pragma unroll
        for (int nt = 0; nt < 4; ++nt) {
            s[nt] = (f32x4){0.f, 0.f, 0.f, 0.f};
#pragma unroll
            for (int ks = 0; ks < 2; ++ks) {
                short8v kf = *(const short8v*)&Ks[nt * 16 + col][ks * 32 + q4 * 8];
                s[nt] = __builtin_amdgcn_mfma_f32_16x16x32_bf16(qfrag[ks], kf, s[nt], 0, 0, 0);
            }
        }
        // scale by 1/sqrt(64)
#pragma unroll
        for (int nt = 0; nt < 4; ++nt)
#pragma unroll
            for (int r = 0; r < 4; ++r) s[nt][r] *= 0.125f;

        // online softmax
        float mx[4];
#pragma unroll
        for (int r = 0; r < 4; ++r) {
            mx[r] = fmaxf(fmaxf(s[0][r], s[1][r]), fmaxf(s[2][r], s[3][r]));
            mx[r] = fmaxf(mx[r], __shfl_xor(mx[r], 1));
            mx[r] = fmaxf(mx[r], __shfl_xor(mx[r], 2));
            mx[r] = fmaxf(mx[r], __shfl_xor(mx[r], 4));
            mx[r] = fmaxf(mx[r], __shfl_xor(mx[r], 8));
        }
        float cf[4], rs[4];
#pragma unroll
        for (int r = 0; r < 4; ++r) {
            const float mnew = fmaxf(m[r], mx[r]);
            cf[r] = __expf(m[r] - mnew);
            m[r] = mnew;
            rs[r] = 0.f;
        }
#pragma unroll
        for (int nt = 0; nt < 4; ++nt)
#pragma unroll
            for (int r = 0; r < 4; ++r) {
                const float p = __expf(s[nt][r] - m[r]);
                s[nt][r] = p;
                rs[r] += p;
            }
#pragma unroll
        for (int r = 0; r < 4; ++r) {
            rs[r] += __shfl_xor(rs[r], 1);
            rs[r] += __shfl_xor(rs[r], 2);
            rs[r] += __shfl_xor(rs[r], 4);
            rs[r] += __shfl_xor(rs[r], 8);
            l[r] = l[r] * cf[r] + rs[r];
        }
#pragma unroll
        for (int nt = 0; nt < 4; ++nt)
#pragma unroll
            for (int r = 0; r < 4; ++r) o[nt][r] *= cf[r];

        // P -> LDS (per-wave), read back as A fragments
#pragma unroll
        for (int nt = 0; nt < 4; ++nt)
#pragma unroll
            for (int r = 0; r < 4; ++r)
                Ps[wave][q4 * 4 + r][nt * 16 + col] = f2bf(s[nt][r]);

        short8v pf0 = *(const short8v*)&Ps[wave][col][q4 * 8];
        short8v pf1 = *(const short8v*)&Ps[wave][col][32 + q4 * 8];
#pragma unroll
        for (int nt = 0; nt < 4; ++nt) {
            short8v vf0 = *(const short8v*)&Vt[nt * 16 + col][q4 * 8];
            short8v vf1 = *(const short8v*)&Vt[nt * 16 + col][32 + q4 * 8];
            o[nt] = __builtin_amdgcn_mfma_f32_16x16x32_bf16(pf0, vf0, o[nt], 0, 0, 0);
            o[nt] = __builtin_amdgcn_mfma_f32_16x16x32_bf16(pf1, vf1, o[nt], 0, 0, 0);
        }
    }

#pragma unroll
    for (int r = 0; r < 4; ++r) {
        const float il = 1.0f / l[r];
        float* dst = aout + (size_t)(qrow0 + q4 * 4 + r) * D_MODEL + h * D_HEAD;
#pragma unroll
        for (int nt = 0; nt < 4; ++nt)
            dst[nt * 16 + col] = o[nt][r] * il;
    }
}

// ---------------------------------------------------------------------------
extern "C" void kernel_launch(void* const* d_in, const int* in_sizes, int n_in,
                              void* d_out, int out_size, void* d_ws, size_t ws_size,
                              hipStream_t stream) {
    (void)in_sizes; (void)n_in; (void)out_size; (void)ws_size;

    const float* x     = (const float*)d_in[0];
    const float* w_qkv = (const float*)d_in[1];
    const float* b_qkv = (const float*)d_in[2];
    const float* w_out = (const float*)d_in[3];
    const float* b_out = (const float*)d_in[4];
    float* out = (float*)d_out;

    // ws layout (bytes):
    char* ws = (char*)d_ws;
    unsigned short* qkv_bf   = (unsigned short*)ws;                      // 4096*3072*2 = 25.2 MB
    float*          attn_f   = (float*)(ws + 25165824);                  // 4096*1024*4 = 16.8 MB
    unsigned short* wqkvT_h  = (unsigned short*)(ws + 25165824 + 16777216);            // 3072*1024*2
    unsigned short* wqkvT_l  = wqkvT_h + (size_t)3 * D_MODEL * D_MODEL;                // 3072*1024*2
    unsigned short* woutT_h  = wqkvT_l + (size_t)3 * D_MODEL * D_MODEL;                // 1024*1024*2
    unsigned short* woutT_l  = woutT_h + (size_t)D_MODEL * D_MODEL;                    // 1024*1024*2

    // 1) weight transpose+split
    splitT_kernel<<<dim3((D_MODEL / 64) * (3 * D_MODEL / 64)), 256, 0, stream>>>(
        w_qkv, wqkvT_h, wqkvT_l, D_MODEL, 3 * D_MODEL);
    splitT_kernel<<<dim3((D_MODEL / 64) * (D_MODEL / 64)), 256, 0, stream>>>(
        w_out, woutT_h, woutT_l, D_MODEL, D_MODEL);

    // 2) QKV projection -> bf16 qkv
    gemm_split_kernel<1><<<dim3((NROWS / 128) * (3 * D_MODEL / 128)), 256, 0, stream>>>(
        x, wqkvT_h, wqkvT_l, b_qkv, (void*)qkv_bf, NROWS, 3 * D_MODEL, D_MODEL);

    // 3) flash attention -> fp32
    attn_mfma_kernel<<<dim3(NBATCH * N_HEADS, SEQ / 64), 256, 0, stream>>>(qkv_bf, attn_f);

    // 4) output projection -> fp32 out
    gemm_split_kernel<0><<<dim3((NROWS / 128) * (D_MODEL / 128)), 256, 0, stream>>>(
        attn_f, woutT_h, woutT_l, b_out, (void*)out, NROWS, D_MODEL, D_MODEL);
}

// Round 4
// 271.998 us; speedup vs baseline: 5.9657x; 1.1324x over previous
//
#include <hip/hip_runtime.h>
#include <hip/hip_bf16.h>
#include <math.h>

#define D_MODEL 1024
#define N_HEADS 16
#define D_HEAD  64
#define SEQ     2048
#define NBATCH  2
#define NROWS   (NBATCH * SEQ)      // 4096

typedef __attribute__((ext_vector_type(8))) short short8v;        // 8 bf16
typedef __attribute__((ext_vector_type(4))) float f32x4;
typedef __attribute__((ext_vector_type(4))) unsigned int u32x4;

__device__ __forceinline__ unsigned short f2bf(float x) {
    unsigned int u = __float_as_uint(x);
    return (unsigned short)((u + 0x7FFFu + ((u >> 16) & 1u)) >> 16);   // RNE
}
// truncation split: hi = top-16-bits of fp32, lo = RNE(x - hi)
__device__ __forceinline__ void split_bf(float x, unsigned short& hi, unsigned short& lo) {
    unsigned int u = __float_as_uint(x);
    unsigned int ht = u & 0xFFFF0000u;
    hi = (unsigned short)(ht >> 16);
    lo = f2bf(x - __uint_as_float(ht));
}
// packed RNE f32x2 -> bf16x2 (low16 = first arg, high16 = second arg)
__device__ __forceinline__ unsigned int cvtpk(float lo, float hi) {
    unsigned int r;
    asm("v_cvt_pk_bf16_f32 %0, %1, %2" : "=v"(r) : "v"(lo), "v"(hi));
    return r;
}

// ---------------------------------------------------------------------------
// Weight transpose + split: W[K][N] fp32 -> Th[N][K], Tl[N][K] bf16
// ---------------------------------------------------------------------------
__global__ __launch_bounds__(256) void splitT_kernel(
    const float* __restrict__ W, unsigned short* __restrict__ Th,
    unsigned short* __restrict__ Tl, int K, int N)
{
    __shared__ float tile[64][68];
    const int tid = threadIdx.x;
    const int nbn = N >> 6;
    const int k0 = (blockIdx.x / nbn) << 6;
    const int n0 = (blockIdx.x % nbn) << 6;
    const int r  = tid >> 4;
    const int c4 = (tid & 15) * 4;

#pragma unroll
    for (int i = 0; i < 4; ++i) {
        float4 v = *(const float4*)(W + (size_t)(k0 + r + i * 16) * N + n0 + c4);
        *(float4*)&tile[r + i * 16][c4] = v;
    }
    __syncthreads();

    const int kl = (tid & 15) * 4;
#pragma unroll
    for (int i = 0; i < 4; ++i) {
        const int nl = (tid >> 4) + i * 16;
        ushort4 h4, l4;
        unsigned short h, l;
        split_bf(tile[kl + 0][nl], h, l); h4.x = h; l4.x = l;
        split_bf(tile[kl + 1][nl], h, l); h4.y = h; l4.y = l;
        split_bf(tile[kl + 2][nl], h, l); h4.z = h; l4.z = l;
        split_bf(tile[kl + 3][nl], h, l); h4.w = h; l4.w = l;
        *(ushort4*)(Th + (size_t)(n0 + nl) * K + k0 + kl) = h4;
        *(ushort4*)(Tl + (size_t)(n0 + nl) * K + k0 + kl) = l4;
    }
}

// ---------------------------------------------------------------------------
// GEMM1: qkv[M,N](bf16) = RNE_bf16(A[M,K] fp32) @ (Bh+Bl)[N,K]^T + bias
// 2-term MFMA. Tile 128x128x32, 4 waves (2x2), 64x64 each.
// ---------------------------------------------------------------------------
#define ASTRIDE 40    // bf16 elems; 80B row stride

__global__ __launch_bounds__(256) void gemm_xw_kernel(
    const float* __restrict__ A,
    const unsigned short* __restrict__ Bth,
    const unsigned short* __restrict__ Btl,
    const float* __restrict__ bias,
    unsigned short* __restrict__ C, int M, int N, int K)
{
    __shared__ __align__(16) unsigned short Ab[128][ASTRIDE];
    __shared__ __align__(16) unsigned short Bh[128][ASTRIDE];
    __shared__ __align__(16) unsigned short Bl[128][ASTRIDE];

    const int tid  = threadIdx.x;
    const int wave = tid >> 6;
    const int lane = tid & 63;
    const int col  = lane & 15;
    const int q4   = lane >> 4;
    const int wm   = (wave >> 1) * 64;
    const int wn   = (wave & 1) * 64;

    const int nwg = gridDim.x;
    const int cpx = nwg >> 3;
    const int swz = (blockIdx.x & 7) * cpx + (blockIdx.x >> 3);
    const int nbn = N / 128;
    const int bm = (swz / nbn) * 128;
    const int bn = (swz % nbn) * 128;

    const int sr = tid >> 1;
    const int sq = (tid & 1) * 16;
    const float* aptr = A + (size_t)(bm + sr) * K + sq;
    const unsigned short* bhp = Bth + (size_t)(bn + sr) * K + sq;
    const unsigned short* blp = Btl + (size_t)(bn + sr) * K + sq;

    f32x4 acc[4][4];
#pragma unroll
    for (int i = 0; i < 4; ++i)
#pragma unroll
        for (int j = 0; j < 4; ++j) acc[i][j] = (f32x4){0.f, 0.f, 0.f, 0.f};

    for (int k0 = 0; k0 < K; k0 += 32) {
        float4 a0 = *(const float4*)(aptr + k0);
        float4 a1 = *(const float4*)(aptr + k0 + 4);
        float4 a2 = *(const float4*)(aptr + k0 + 8);
        float4 a3 = *(const float4*)(aptr + k0 + 12);
        short8v b0h = *(const short8v*)(bhp + k0);
        short8v b1h = *(const short8v*)(bhp + k0 + 8);
        short8v b0l = *(const short8v*)(blp + k0);
        short8v b1l = *(const short8v*)(blp + k0 + 8);

        __syncthreads();
        {
            u32x4 p0, p1;
            p0.x = cvtpk(a0.x, a0.y); p0.y = cvtpk(a0.z, a0.w);
            p0.z = cvtpk(a1.x, a1.y); p0.w = cvtpk(a1.z, a1.w);
            p1.x = cvtpk(a2.x, a2.y); p1.y = cvtpk(a2.z, a2.w);
            p1.z = cvtpk(a3.x, a3.y); p1.w = cvtpk(a3.z, a3.w);
            *(u32x4*)&Ab[sr][sq]     = p0;
            *(u32x4*)&Ab[sr][sq + 8] = p1;
            *(short8v*)&Bh[sr][sq]     = b0h;
            *(short8v*)&Bh[sr][sq + 8] = b1h;
            *(short8v*)&Bl[sr][sq]     = b0l;
            *(short8v*)&Bl[sr][sq + 8] = b1l;
        }
        __syncthreads();

        short8v af[4];
#pragma unroll
        for (int mt = 0; mt < 4; ++mt)
            af[mt] = *(const short8v*)&Ab[wm + mt * 16 + col][q4 * 8];
#pragma unroll
        for (int nt = 0; nt < 4; ++nt) {
            short8v bhf = *(const short8v*)&Bh[wn + nt * 16 + col][q4 * 8];
            short8v blf = *(const short8v*)&Bl[wn + nt * 16 + col][q4 * 8];
#pragma unroll
            for (int mt = 0; mt < 4; ++mt) {
                acc[mt][nt] = __builtin_amdgcn_mfma_f32_16x16x32_bf16(af[mt], bhf, acc[mt][nt], 0, 0, 0);
                acc[mt][nt] = __builtin_amdgcn_mfma_f32_16x16x32_bf16(af[mt], blf, acc[mt][nt], 0, 0, 0);
            }
        }
    }

    float bv[4];
#pragma unroll
    for (int nt = 0; nt < 4; ++nt) bv[nt] = bias[bn + wn + nt * 16 + col];

#pragma unroll
    for (int mt = 0; mt < 4; ++mt)
#pragma unroll
        for (int r = 0; r < 4; ++r) {
            const int row = bm + wm + mt * 16 + q4 * 4 + r;
#pragma unroll
            for (int nt = 0; nt < 4; ++nt)
                C[(size_t)row * N + bn + wn + nt * 16 + col] = f2bf(acc[mt][nt][r] + bv[nt]);
        }
}

// ---------------------------------------------------------------------------
// GEMM2: out[M,N](fp32) = (Aoh+Aol)[M,K] @ (Bh+Bl)[N,K]^T + bias, 3-term.
// A pre-split by the attention kernel -> staging is pure copies.
// ---------------------------------------------------------------------------
__global__ __launch_bounds__(256) void gemm_ao_kernel(
    const unsigned short* __restrict__ Aoh,
    const unsigned short* __restrict__ Aol,
    const unsigned short* __restrict__ Bth,
    const unsigned short* __restrict__ Btl,
    const float* __restrict__ bias,
    float* __restrict__ C, int M, int N, int K)
{
    __shared__ __align__(16) unsigned short Ah[128][ASTRIDE];
    __shared__ __align__(16) unsigned short Al[128][ASTRIDE];
    __shared__ __align__(16) unsigned short Bh[128][ASTRIDE];
    __shared__ __align__(16) unsigned short Bl[128][ASTRIDE];

    const int tid  = threadIdx.x;
    const int wave = tid >> 6;
    const int lane = tid & 63;
    const int col  = lane & 15;
    const int q4   = lane >> 4;
    const int wm   = (wave >> 1) * 64;
    const int wn   = (wave & 1) * 64;

    const int nwg = gridDim.x;
    const int cpx = nwg >> 3;
    const int swz = (blockIdx.x & 7) * cpx + (blockIdx.x >> 3);
    const int nbn = N / 128;
    const int bm = (swz / nbn) * 128;
    const int bn = (swz % nbn) * 128;

    const int sr = tid >> 1;
    const int sq = (tid & 1) * 16;
    const unsigned short* ahp = Aoh + (size_t)(bm + sr) * K + sq;
    const unsigned short* alp = Aol + (size_t)(bm + sr) * K + sq;
    const unsigned short* bhp = Bth + (size_t)(bn + sr) * K + sq;
    const unsigned short* blp = Btl + (size_t)(bn + sr) * K + sq;

    f32x4 acc[4][4];
#pragma unroll
    for (int i = 0; i < 4; ++i)
#pragma unroll
        for (int j = 0; j < 4; ++j) acc[i][j] = (f32x4){0.f, 0.f, 0.f, 0.f};

    for (int k0 = 0; k0 < K; k0 += 32) {
        short8v a0h = *(const short8v*)(ahp + k0);
        short8v a1h = *(const short8v*)(ahp + k0 + 8);
        short8v a0l = *(const short8v*)(alp + k0);
        short8v a1l = *(const short8v*)(alp + k0 + 8);
        short8v b0h = *(const short8v*)(bhp + k0);
        short8v b1h = *(const short8v*)(bhp + k0 + 8);
        short8v b0l = *(const short8v*)(blp + k0);
        short8v b1l = *(const short8v*)(blp + k0 + 8);

        __syncthreads();
        *(short8v*)&Ah[sr][sq]     = a0h;
        *(short8v*)&Ah[sr][sq + 8] = a1h;
        *(short8v*)&Al[sr][sq]     = a0l;
        *(short8v*)&Al[sr][sq + 8] = a1l;
        *(short8v*)&Bh[sr][sq]     = b0h;
        *(short8v*)&Bh[sr][sq + 8] = b1h;
        *(short8v*)&Bl[sr][sq]     = b0l;
        *(short8v*)&Bl[sr][sq + 8] = b1l;
        __syncthreads();

        short8v ahf[4], alf[4];
#pragma unroll
        for (int mt = 0; mt < 4; ++mt) {
            ahf[mt] = *(const short8v*)&Ah[wm + mt * 16 + col][q4 * 8];
            alf[mt] = *(const short8v*)&Al[wm + mt * 16 + col][q4 * 8];
        }
#pragma unroll
        for (int nt = 0; nt < 4; ++nt) {
            short8v bhf = *(const short8v*)&Bh[wn + nt * 16 + col][q4 * 8];
            short8v blf = *(const short8v*)&Bl[wn + nt * 16 + col][q4 * 8];
#pragma unroll
            for (int mt = 0; mt < 4; ++mt) {
                acc[mt][nt] = __builtin_amdgcn_mfma_f32_16x16x32_bf16(ahf[mt], bhf, acc[mt][nt], 0, 0, 0);
                acc[mt][nt] = __builtin_amdgcn_mfma_f32_16x16x32_bf16(alf[mt], bhf, acc[mt][nt], 0, 0, 0);
                acc[mt][nt] = __builtin_amdgcn_mfma_f32_16x16x32_bf16(ahf[mt], blf, acc[mt][nt], 0, 0, 0);
            }
        }
    }

    float bv[4];
#pragma unroll
    for (int nt = 0; nt < 4; ++nt) bv[nt] = bias[bn + wn + nt * 16 + col];

#pragma unroll
    for (int mt = 0; mt < 4; ++mt)
#pragma unroll
        for (int r = 0; r < 4; ++r) {
            const int row = bm + wm + mt * 16 + q4 * 4 + r;
#pragma unroll
            for (int nt = 0; nt < 4; ++nt)
                C[(size_t)row * N + bn + wn + nt * 16 + col] = acc[mt][nt][r] + bv[nt];
        }
}

// ---------------------------------------------------------------------------
// MFMA flash attention. bf16 qkv [4096][3072] in; split bf16 (hi/lo) out.
// XOR-swizzled LDS (128B rows, elem ^= (row&7)<<3) -> 2-way banks (free).
// exp2-domain online softmax (scale folded into the exponent FMA).
// ---------------------------------------------------------------------------
#define KBLK 64

__global__ __launch_bounds__(256) void attn_mfma_kernel(
    const unsigned short* __restrict__ qkv,
    unsigned short* __restrict__ aoh, unsigned short* __restrict__ aol)
{
    __shared__ __align__(16) unsigned short Ks[64 * 64];      // [key][dim] swizzled
    __shared__ __align__(16) unsigned short Vt[64 * 64];      // [dim][key] swizzled
    __shared__ __align__(16) unsigned short Ps[4][16 * 64];   // per-wave [qrow][key] swizzled

    const int tid  = threadIdx.x;
    const int wave = tid >> 6;
    const int lane = tid & 63;
    const int col  = lane & 15;
    const int q4   = lane >> 4;

    const int bh = blockIdx.x;
    const int qt = blockIdx.y;
    const int b = bh >> 4;
    const int h = bh & 15;
    const int qrow0 = b * SEQ + qt * 64 + wave * 16;
    const int krow0 = b * SEQ;

    short8v qfrag[2];
    {
        const unsigned short* qsrc = qkv + (size_t)(qrow0 + col) * (3 * D_MODEL) + h * D_HEAD;
        qfrag[0] = *(const short8v*)(qsrc + q4 * 8);
        qfrag[1] = *(const short8v*)(qsrc + 32 + q4 * 8);
    }

    const int vd4   = (tid & 15) * 4;
    const int vkey0 = (tid >> 4) * 4;

    f32x4 o[4];
#pragma unroll
    for (int nt = 0; nt < 4; ++nt) o[nt] = (f32x4){0.f, 0.f, 0.f, 0.f};
    float m2[4], l[4];
#pragma unroll
    for (int r = 0; r < 4; ++r) { m2[r] = -1e30f; l[r] = 0.f; }

    const float C2 = 0.18033688011112042f;   // 0.125 * log2(e)

    for (int kc = 0; kc < SEQ; kc += KBLK) {
        short8v kv[2];
        int kkey[2], kcb[2];
#pragma unroll
        for (int it = 0; it < 2; ++it) {
            const int c = it * 256 + tid;
            kkey[it] = c >> 3;
            kcb[it]  = (c & 7) * 8;
            kv[it] = *(const short8v*)(qkv + (size_t)(krow0 + kc + kkey[it]) * (3 * D_MODEL)
                                       + D_MODEL + h * D_HEAD + kcb[it]);
        }
        ushort4 vr[4];
#pragma unroll
        for (int i = 0; i < 4; ++i)
            vr[i] = *(const ushort4*)(qkv + (size_t)(krow0 + kc + vkey0 + i) * (3 * D_MODEL)
                                      + 2 * D_MODEL + h * D_HEAD + vd4);

        __syncthreads();

#pragma unroll
        for (int it = 0; it < 2; ++it) {
            const int e = (kkey[it] * 64 + kcb[it]) ^ ((kkey[it] & 7) << 3);
            *(short8v*)&Ks[e] = kv[it];
        }
#pragma unroll
        for (int j = 0; j < 4; ++j) {
            ushort4 w;
            w.x = ((const unsigned short*)&vr[0])[j];
            w.y = ((const unsigned short*)&vr[1])[j];
            w.z = ((const unsigned short*)&vr[2])[j];
            w.w = ((const unsigned short*)&vr[3])[j];
            const int row = vd4 + j;
            const int e = (row * 64 + vkey0) ^ ((row & 7) << 3);
            *(ushort4*)&Vt[e] = w;
        }
        __syncthreads();

        f32x4 s[4];
#pragma unroll
        for (int nt = 0; nt < 4; ++nt) {
            s[nt] = (f32x4){0.f, 0.f, 0.f, 0.f};
            const int krow = nt * 16 + col;
#pragma unroll
            for (int ks = 0; ks < 2; ++ks) {
                const int e = (krow * 64 + ks * 32 + q4 * 8) ^ ((krow & 7) << 3);
                short8v kf = *(const short8v*)&Ks[e];
                s[nt] = __builtin_amdgcn_mfma_f32_16x16x32_bf16(qfrag[ks], kf, s[nt], 0, 0, 0);
            }
        }

        float mx[4];
#pragma unroll
        for (int r = 0; r < 4; ++r) {
            mx[r] = fmaxf(fmaxf(s[0][r], s[1][r]), fmaxf(s[2][r], s[3][r]));
            mx[r] = fmaxf(mx[r], __shfl_xor(mx[r], 1));
            mx[r] = fmaxf(mx[r], __shfl_xor(mx[r], 2));
            mx[r] = fmaxf(mx[r], __shfl_xor(mx[r], 4));
            mx[r] = fmaxf(mx[r], __shfl_xor(mx[r], 8));
        }
        float cf[4], rs[4];
#pragma unroll
        for (int r = 0; r < 4; ++r) {
            const float mnew = fmaxf(m2[r], mx[r] * C2);
            cf[r] = __builtin_exp2f(m2[r] - mnew);
            m2[r] = mnew;
            rs[r] = 0.f;
        }
#pragma unroll
        for (int nt = 0; nt < 4; ++nt)
#pragma unroll
            for (int r = 0; r < 4; ++r) {
                const float p = __builtin_exp2f(fmaf(s[nt][r], C2, -m2[r]));
                s[nt][r] = p;
                rs[r] += p;
            }
#pragma unroll
        for (int r = 0; r < 4; ++r) {
            rs[r] += __shfl_xor(rs[r], 1);
            rs[r] += __shfl_xor(rs[r], 2);
            rs[r] += __shfl_xor(rs[r], 4);
            rs[r] += __shfl_xor(rs[r], 8);
            l[r] = l[r] * cf[r] + rs[r];
        }
#pragma unroll
        for (int nt = 0; nt < 4; ++nt)
#pragma unroll
            for (int r = 0; r < 4; ++r) o[nt][r] *= cf[r];

        const int r0 = q4 * 4;
#pragma unroll
        for (int nt = 0; nt < 4; ++nt) {
            const unsigned int pk01 = cvtpk(s[nt][0], s[nt][1]);
            const unsigned int pk23 = cvtpk(s[nt][2], s[nt][3]);
            const int cbase = nt * 16 + col;
            Ps[wave][((r0 + 0) * 64 + cbase) ^ (((r0 + 0) & 7) << 3)] = (unsigned short)(pk01 & 0xFFFFu);
            Ps[wave][((r0 + 1) * 64 + cbase) ^ (((r0 + 1) & 7) << 3)] = (unsigned short)(pk01 >> 16);
            Ps[wave][((r0 + 2) * 64 + cbase) ^ (((r0 + 2) & 7) << 3)] = (unsigned short)(pk23 & 0xFFFFu);
            Ps[wave][((r0 + 3) * 64 + cbase) ^ (((r0 + 3) & 7) << 3)] = (unsigned short)(pk23 >> 16);
        }

        short8v pf0 = *(const short8v*)&Ps[wave][(col * 64 + q4 * 8) ^ ((col & 7) << 3)];
        short8v pf1 = *(const short8v*)&Ps[wave][(col * 64 + 32 + q4 * 8) ^ ((col & 7) << 3)];
#pragma unroll
        for (int nt = 0; nt < 4; ++nt) {
            const int vrow = nt * 16 + col;
            short8v vf0 = *(const short8v*)&Vt[(vrow * 64 + q4 * 8) ^ ((vrow & 7) << 3)];
            short8v vf1 = *(const short8v*)&Vt[(vrow * 64 + 32 + q4 * 8) ^ ((vrow & 7) << 3)];
            o[nt] = __builtin_amdgcn_mfma_f32_16x16x32_bf16(pf0, vf0, o[nt], 0, 0, 0);
            o[nt] = __builtin_amdgcn_mfma_f32_16x16x32_bf16(pf1, vf1, o[nt], 0, 0, 0);
        }
    }

#pragma unroll
    for (int r = 0; r < 4; ++r) {
        const float il = 1.0f / l[r];
        const size_t rbase = (size_t)(qrow0 + q4 * 4 + r) * D_MODEL + h * D_HEAD;
#pragma unroll
        for (int nt = 0; nt < 4; ++nt) {
            unsigned short hi, lo;
            split_bf(o[nt][r] * il, hi, lo);
            aoh[rbase + nt * 16 + col] = hi;
            aol[rbase + nt * 16 + col] = lo;
        }
    }
}

// ---------------------------------------------------------------------------
extern "C" void kernel_launch(void* const* d_in, const int* in_sizes, int n_in,
                              void* d_out, int out_size, void* d_ws, size_t ws_size,
                              hipStream_t stream) {
    (void)in_sizes; (void)n_in; (void)out_size; (void)ws_size;

    const float* x     = (const float*)d_in[0];
    const float* w_qkv = (const float*)d_in[1];
    const float* b_qkv = (const float*)d_in[2];
    const float* w_out = (const float*)d_in[3];
    const float* b_out = (const float*)d_in[4];
    float* out = (float*)d_out;

    char* ws = (char*)d_ws;
    unsigned short* qkv_bf  = (unsigned short*)(ws);                       // 25,165,824 B
    unsigned short* aoh     = (unsigned short*)(ws + 25165824);            //  8,388,608 B
    unsigned short* aol     = (unsigned short*)(ws + 33554432);            //  8,388,608 B
    unsigned short* wqkvT_h = (unsigned short*)(ws + 41943040);            //  6,291,456 B
    unsigned short* wqkvT_l = (unsigned short*)(ws + 48234496);            //  6,291,456 B
    unsigned short* woutT_h = (unsigned short*)(ws + 54525952);            //  2,097,152 B
    unsigned short* woutT_l = (unsigned short*)(ws + 56623104);            //  2,097,152 B

    splitT_kernel<<<dim3((D_MODEL / 64) * (3 * D_MODEL / 64)), 256, 0, stream>>>(
        w_qkv, wqkvT_h, wqkvT_l, D_MODEL, 3 * D_MODEL);
    splitT_kernel<<<dim3((D_MODEL / 64) * (D_MODEL / 64)), 256, 0, stream>>>(
        w_out, woutT_h, woutT_l, D_MODEL, D_MODEL);

    gemm_xw_kernel<<<dim3((NROWS / 128) * (3 * D_MODEL / 128)), 256, 0, stream>>>(
        x, wqkvT_h, wqkvT_l, b_qkv, qkv_bf, NROWS, 3 * D_MODEL, D_MODEL);

    attn_mfma_kernel<<<dim3(NBATCH * N_HEADS, SEQ / 64), 256, 0, stream>>>(qkv_bf, aoh, aol);

    gemm_ao_kernel<<<dim3((NROWS / 128) * (D_MODEL / 128)), 256, 0, stream>>>(
        aoh, aol, woutT_h, woutT_l, b_out, out, NROWS, D_MODEL, D_MODEL);
}

// Round 5
// 213.441 us; speedup vs baseline: 7.6024x; 1.2743x over previous
//
#include <hip/hip_runtime.h>
#include <hip/hip_bf16.h>
#include <math.h>

#define D_MODEL 1024
#define N_HEADS 16
#define D_HEAD  64
#define SEQ     2048
#define NBATCH  2
#define NROWS   (NBATCH * SEQ)      // 4096

typedef __attribute__((ext_vector_type(8))) short short8v;        // 8 bf16
typedef __attribute__((ext_vector_type(4))) float f32x4;
typedef __attribute__((ext_vector_type(16))) float f32x16;
typedef __attribute__((ext_vector_type(4))) unsigned int u32x4;

__device__ __forceinline__ unsigned short f2bf(float x) {
    unsigned int u = __float_as_uint(x);
    return (unsigned short)((u + 0x7FFFu + ((u >> 16) & 1u)) >> 16);   // RNE
}
// truncation split: hi = top-16-bits of fp32, lo = RNE(x - hi)
__device__ __forceinline__ void split_bf(float x, unsigned short& hi, unsigned short& lo) {
    unsigned int u = __float_as_uint(x);
    unsigned int ht = u & 0xFFFF0000u;
    hi = (unsigned short)(ht >> 16);
    lo = f2bf(x - __uint_as_float(ht));
}
// packed RNE f32x2 -> bf16x2 (low16 = first arg, high16 = second arg)
__device__ __forceinline__ unsigned int cvtpk(float lo, float hi) {
    unsigned int r;
    asm("v_cvt_pk_bf16_f32 %0, %1, %2" : "=v"(r) : "v"(lo), "v"(hi));
    return r;
}
__device__ __forceinline__ short8v u2s(u32x4 v) {
    union { u32x4 u; short8v s; } c; c.u = v; return c.s;
}

// ---------------------------------------------------------------------------
// Weight transpose + split: W[K][N] fp32 -> Th[N][K], Tl[N][K] bf16
// ---------------------------------------------------------------------------
__global__ __launch_bounds__(256) void splitT_kernel(
    const float* __restrict__ W, unsigned short* __restrict__ Th,
    unsigned short* __restrict__ Tl, int K, int N)
{
    __shared__ float tile[64][68];
    const int tid = threadIdx.x;
    const int nbn = N >> 6;
    const int k0 = (blockIdx.x / nbn) << 6;
    const int n0 = (blockIdx.x % nbn) << 6;
    const int r  = tid >> 4;
    const int c4 = (tid & 15) * 4;

#pragma unroll
    for (int i = 0; i < 4; ++i) {
        float4 v = *(const float4*)(W + (size_t)(k0 + r + i * 16) * N + n0 + c4);
        *(float4*)&tile[r + i * 16][c4] = v;
    }
    __syncthreads();

    const int kl = (tid & 15) * 4;
#pragma unroll
    for (int i = 0; i < 4; ++i) {
        const int nl = (tid >> 4) + i * 16;
        ushort4 h4, l4;
        unsigned short h, l;
        split_bf(tile[kl + 0][nl], h, l); h4.x = h; l4.x = l;
        split_bf(tile[kl + 1][nl], h, l); h4.y = h; l4.y = l;
        split_bf(tile[kl + 2][nl], h, l); h4.z = h; l4.z = l;
        split_bf(tile[kl + 3][nl], h, l); h4.w = h; l4.w = l;
        *(ushort4*)(Th + (size_t)(n0 + nl) * K + k0 + kl) = h4;
        *(ushort4*)(Tl + (size_t)(n0 + nl) * K + k0 + kl) = l4;
    }
}

// ---------------------------------------------------------------------------
// GEMM1: qkv[M,N](bf16) = RNE_bf16(A[M,K] fp32) @ (Bh+Bl)[N,K]^T + bias
// ---------------------------------------------------------------------------
#define ASTRIDE 40    // bf16 elems; 80B row stride

__global__ __launch_bounds__(256) void gemm_xw_kernel(
    const float* __restrict__ A,
    const unsigned short* __restrict__ Bth,
    const unsigned short* __restrict__ Btl,
    const float* __restrict__ bias,
    unsigned short* __restrict__ C, int M, int N, int K)
{
    __shared__ __align__(16) unsigned short Ab[128][ASTRIDE];
    __shared__ __align__(16) unsigned short Bh[128][ASTRIDE];
    __shared__ __align__(16) unsigned short Bl[128][ASTRIDE];

    const int tid  = threadIdx.x;
    const int wave = tid >> 6;
    const int lane = tid & 63;
    const int col  = lane & 15;
    const int q4   = lane >> 4;
    const int wm   = (wave >> 1) * 64;
    const int wn   = (wave & 1) * 64;

    const int nwg = gridDim.x;
    const int cpx = nwg >> 3;
    const int swz = (blockIdx.x & 7) * cpx + (blockIdx.x >> 3);
    const int nbn = N / 128;
    const int bm = (swz / nbn) * 128;
    const int bn = (swz % nbn) * 128;

    const int sr = tid >> 1;
    const int sq = (tid & 1) * 16;
    const float* aptr = A + (size_t)(bm + sr) * K + sq;
    const unsigned short* bhp = Bth + (size_t)(bn + sr) * K + sq;
    const unsigned short* blp = Btl + (size_t)(bn + sr) * K + sq;

    f32x4 acc[4][4];
#pragma unroll
    for (int i = 0; i < 4; ++i)
#pragma unroll
        for (int j = 0; j < 4; ++j) acc[i][j] = (f32x4){0.f, 0.f, 0.f, 0.f};

    for (int k0 = 0; k0 < K; k0 += 32) {
        float4 a0 = *(const float4*)(aptr + k0);
        float4 a1 = *(const float4*)(aptr + k0 + 4);
        float4 a2 = *(const float4*)(aptr + k0 + 8);
        float4 a3 = *(const float4*)(aptr + k0 + 12);
        short8v b0h = *(const short8v*)(bhp + k0);
        short8v b1h = *(const short8v*)(bhp + k0 + 8);
        short8v b0l = *(const short8v*)(blp + k0);
        short8v b1l = *(const short8v*)(blp + k0 + 8);

        __syncthreads();
        {
            u32x4 p0, p1;
            p0.x = cvtpk(a0.x, a0.y); p0.y = cvtpk(a0.z, a0.w);
            p0.z = cvtpk(a1.x, a1.y); p0.w = cvtpk(a1.z, a1.w);
            p1.x = cvtpk(a2.x, a2.y); p1.y = cvtpk(a2.z, a2.w);
            p1.z = cvtpk(a3.x, a3.y); p1.w = cvtpk(a3.z, a3.w);
            *(u32x4*)&Ab[sr][sq]     = p0;
            *(u32x4*)&Ab[sr][sq + 8] = p1;
            *(short8v*)&Bh[sr][sq]     = b0h;
            *(short8v*)&Bh[sr][sq + 8] = b1h;
            *(short8v*)&Bl[sr][sq]     = b0l;
            *(short8v*)&Bl[sr][sq + 8] = b1l;
        }
        __syncthreads();

        short8v af[4];
#pragma unroll
        for (int mt = 0; mt < 4; ++mt)
            af[mt] = *(const short8v*)&Ab[wm + mt * 16 + col][q4 * 8];
#pragma unroll
        for (int nt = 0; nt < 4; ++nt) {
            short8v bhf = *(const short8v*)&Bh[wn + nt * 16 + col][q4 * 8];
            short8v blf = *(const short8v*)&Bl[wn + nt * 16 + col][q4 * 8];
#pragma unroll
            for (int mt = 0; mt < 4; ++mt) {
                acc[mt][nt] = __builtin_amdgcn_mfma_f32_16x16x32_bf16(af[mt], bhf, acc[mt][nt], 0, 0, 0);
                acc[mt][nt] = __builtin_amdgcn_mfma_f32_16x16x32_bf16(af[mt], blf, acc[mt][nt], 0, 0, 0);
            }
        }
    }

    float bv[4];
#pragma unroll
    for (int nt = 0; nt < 4; ++nt) bv[nt] = bias[bn + wn + nt * 16 + col];

#pragma unroll
    for (int mt = 0; mt < 4; ++mt)
#pragma unroll
        for (int r = 0; r < 4; ++r) {
            const int row = bm + wm + mt * 16 + q4 * 4 + r;
#pragma unroll
            for (int nt = 0; nt < 4; ++nt)
                C[(size_t)row * N + bn + wn + nt * 16 + col] = f2bf(acc[mt][nt][r] + bv[nt]);
        }
}

// ---------------------------------------------------------------------------
// GEMM2: out[M,N](fp32) = (Aoh+Aol)[M,K] @ (Bh+Bl)[N,K]^T + bias, 3-term.
// ---------------------------------------------------------------------------
__global__ __launch_bounds__(256) void gemm_ao_kernel(
    const unsigned short* __restrict__ Aoh,
    const unsigned short* __restrict__ Aol,
    const unsigned short* __restrict__ Bth,
    const unsigned short* __restrict__ Btl,
    const float* __restrict__ bias,
    float* __restrict__ C, int M, int N, int K)
{
    __shared__ __align__(16) unsigned short Ah[128][ASTRIDE];
    __shared__ __align__(16) unsigned short Al[128][ASTRIDE];
    __shared__ __align__(16) unsigned short Bh[128][ASTRIDE];
    __shared__ __align__(16) unsigned short Bl[128][ASTRIDE];

    const int tid  = threadIdx.x;
    const int wave = tid >> 6;
    const int lane = tid & 63;
    const int col  = lane & 15;
    const int q4   = lane >> 4;
    const int wm   = (wave >> 1) * 64;
    const int wn   = (wave & 1) * 64;

    const int nwg = gridDim.x;
    const int cpx = nwg >> 3;
    const int swz = (blockIdx.x & 7) * cpx + (blockIdx.x >> 3);
    const int nbn = N / 128;
    const int bm = (swz / nbn) * 128;
    const int bn = (swz % nbn) * 128;

    const int sr = tid >> 1;
    const int sq = (tid & 1) * 16;
    const unsigned short* ahp = Aoh + (size_t)(bm + sr) * K + sq;
    const unsigned short* alp = Aol + (size_t)(bm + sr) * K + sq;
    const unsigned short* bhp = Bth + (size_t)(bn + sr) * K + sq;
    const unsigned short* blp = Btl + (size_t)(bn + sr) * K + sq;

    f32x4 acc[4][4];
#pragma unroll
    for (int i = 0; i < 4; ++i)
#pragma unroll
        for (int j = 0; j < 4; ++j) acc[i][j] = (f32x4){0.f, 0.f, 0.f, 0.f};

    for (int k0 = 0; k0 < K; k0 += 32) {
        short8v a0h = *(const short8v*)(ahp + k0);
        short8v a1h = *(const short8v*)(ahp + k0 + 8);
        short8v a0l = *(const short8v*)(alp + k0);
        short8v a1l = *(const short8v*)(alp + k0 + 8);
        short8v b0h = *(const short8v*)(bhp + k0);
        short8v b1h = *(const short8v*)(bhp + k0 + 8);
        short8v b0l = *(const short8v*)(blp + k0);
        short8v b1l = *(const short8v*)(blp + k0 + 8);

        __syncthreads();
        *(short8v*)&Ah[sr][sq]     = a0h;
        *(short8v*)&Ah[sr][sq + 8] = a1h;
        *(short8v*)&Al[sr][sq]     = a0l;
        *(short8v*)&Al[sr][sq + 8] = a1l;
        *(short8v*)&Bh[sr][sq]     = b0h;
        *(short8v*)&Bh[sr][sq + 8] = b1h;
        *(short8v*)&Bl[sr][sq]     = b0l;
        *(short8v*)&Bl[sr][sq + 8] = b1l;
        __syncthreads();

        short8v ahf[4], alf[4];
#pragma unroll
        for (int mt = 0; mt < 4; ++mt) {
            ahf[mt] = *(const short8v*)&Ah[wm + mt * 16 + col][q4 * 8];
            alf[mt] = *(const short8v*)&Al[wm + mt * 16 + col][q4 * 8];
        }
#pragma unroll
        for (int nt = 0; nt < 4; ++nt) {
            short8v bhf = *(const short8v*)&Bh[wn + nt * 16 + col][q4 * 8];
            short8v blf = *(const short8v*)&Bl[wn + nt * 16 + col][q4 * 8];
#pragma unroll
            for (int mt = 0; mt < 4; ++mt) {
                acc[mt][nt] = __builtin_amdgcn_mfma_f32_16x16x32_bf16(ahf[mt], bhf, acc[mt][nt], 0, 0, 0);
                acc[mt][nt] = __builtin_amdgcn_mfma_f32_16x16x32_bf16(alf[mt], bhf, acc[mt][nt], 0, 0, 0);
                acc[mt][nt] = __builtin_amdgcn_mfma_f32_16x16x32_bf16(ahf[mt], blf, acc[mt][nt], 0, 0, 0);
            }
        }
    }

    float bv[4];
#pragma unroll
    for (int nt = 0; nt < 4; ++nt) bv[nt] = bias[bn + wn + nt * 16 + col];

#pragma unroll
    for (int mt = 0; mt < 4; ++mt)
#pragma unroll
        for (int r = 0; r < 4; ++r) {
            const int row = bm + wm + mt * 16 + q4 * 4 + r;
#pragma unroll
            for (int nt = 0; nt < 4; ++nt)
                C[(size_t)row * N + bn + wn + nt * 16 + col] = acc[mt][nt][r] + bv[nt];
        }
}

// ---------------------------------------------------------------------------
// MFMA flash attention, transposed-space, 32x32x16.
// Block: 128 threads = 2 waves. Wave handles 32 q-rows; KBLK=64.
// S^T = K·Q^T  (A=K frags from LDS, B=Q regs; lane holds full q-row of S).
// In-lane softmax + one shfl_xor(32). P packed to bf16 in regs (cvt_pk +
// shfl_xor(32) exchange). O^T = V^T·P^T (A=Vt frags, B=P regs).
// LDS: Ks + Vt, 16 KB, XOR-swizzled (^(row&7)<<3 elems), even bank load.
// ---------------------------------------------------------------------------
__global__ __launch_bounds__(128) void attn_mfma_kernel(
    const unsigned short* __restrict__ qkv,
    unsigned short* __restrict__ aoh, unsigned short* __restrict__ aol)
{
    __shared__ __align__(16) unsigned short Ks[64 * 64];   // [key][dim] swizzled
    __shared__ __align__(16) unsigned short Vt[64 * 64];   // [dim][key] swizzled

    const int tid  = threadIdx.x;
    const int wave = tid >> 6;
    const int lane = tid & 63;
    const int l31  = lane & 31;
    const int lh   = lane >> 5;          // 0 or 1
    const bool hihalf = (lh != 0);

    const int bh = blockIdx.x;           // b*16 + h
    const int qt = blockIdx.y;           // 0..31
    const int b = bh >> 4;
    const int h = bh & 15;
    const int qrow0 = b * SEQ + qt * 64 + wave * 32;
    const int krow0 = b * SEQ;

    // Q fragments (B-operand): qf[s][j] = Q[qrow0+l31][s*16 + lh*8 + j]
    short8v qf[4];
    {
        const unsigned short* qsrc = qkv + (size_t)(qrow0 + l31) * (3 * D_MODEL) + h * 64 + lh * 8;
#pragma unroll
        for (int s = 0; s < 4; ++s)
            qf[s] = *(const short8v*)(qsrc + s * 16);
    }

    // staging indices (128 threads)
    const int krow  = tid >> 1;          // 0..63
    const int khalf = (tid & 1) * 32;    // elems (64 B half-row)
    const int vk0   = (tid & 15) * 4;    // 4 keys
    const int vd0   = (tid >> 4) * 8;    // 8 dims (tid>>4 in 0..7)

    f32x16 ot0, ot1;
#pragma unroll
    for (int r = 0; r < 16; ++r) { ot0[r] = 0.f; ot1[r] = 0.f; }
    float m2 = -1e30f, ll = 0.f;
    const float C2 = 0.18033688011112042f;   // 0.125 * log2(e)

    for (int kc = 0; kc < SEQ; kc += 64) {
        // ---- global loads (issued before barrier; overlap prev compute) ----
        const unsigned short* ksrc = qkv + (size_t)(krow0 + kc + krow) * (3 * D_MODEL)
                                     + D_MODEL + h * 64 + khalf;
        short8v kg0 = ((const short8v*)ksrc)[0];
        short8v kg1 = ((const short8v*)ksrc)[1];
        short8v kg2 = ((const short8v*)ksrc)[2];
        short8v kg3 = ((const short8v*)ksrc)[3];
        short8v vg[4];
#pragma unroll
        for (int i = 0; i < 4; ++i)
            vg[i] = *(const short8v*)(qkv + (size_t)(krow0 + kc + vk0 + i) * (3 * D_MODEL)
                                      + 2 * D_MODEL + h * 64 + vd0);

        __syncthreads();   // prev chunk's LDS reads done

        // K row-major, swizzled
        {
            const int base = krow * 64 + khalf;
            const int sw = (krow & 7) << 3;
            *(short8v*)&Ks[(base)      ^ sw] = kg0;
            *(short8v*)&Ks[(base + 8)  ^ sw] = kg1;
            *(short8v*)&Ks[(base + 16) ^ sw] = kg2;
            *(short8v*)&Ks[(base + 24) ^ sw] = kg3;
        }
        // V transposed: Vt[dim][key], swizzled
#pragma unroll
        for (int j = 0; j < 8; ++j) {
            ushort4 w;
            w.x = ((const unsigned short*)&vg[0])[j];
            w.y = ((const unsigned short*)&vg[1])[j];
            w.z = ((const unsigned short*)&vg[2])[j];
            w.w = ((const unsigned short*)&vg[3])[j];
            const int d = vd0 + j;
            *(ushort4*)&Vt[(d * 64 + vk0) ^ ((d & 7) << 3)] = w;
        }
        __syncthreads();

        // ---- S^T = K·Q^T : 2 key-tiles × 4 d-steps ----
        f32x16 st0, st1;
#pragma unroll
        for (int r = 0; r < 16; ++r) { st0[r] = 0.f; st1[r] = 0.f; }
        const int swr = (lane & 7) << 3;
#pragma unroll
        for (int s = 0; s < 4; ++s) {
            short8v kf0 = *(const short8v*)&Ks[(l31 * 64 + s * 16 + lh * 8) ^ swr];
            st0 = __builtin_amdgcn_mfma_f32_32x32x16_bf16(kf0, qf[s], st0, 0, 0, 0);
        }
#pragma unroll
        for (int s = 0; s < 4; ++s) {
            short8v kf1 = *(const short8v*)&Ks[((32 + l31) * 64 + s * 16 + lh * 8) ^ swr];
            st1 = __builtin_amdgcn_mfma_f32_32x32x16_bf16(kf1, qf[s], st1, 0, 0, 0);
        }

        // ---- in-lane online softmax (q = l31 per lane) ----
        float mx = st0[0];
#pragma unroll
        for (int r = 1; r < 16; ++r) mx = fmaxf(mx, st0[r]);
#pragma unroll
        for (int r = 0; r < 16; ++r) mx = fmaxf(mx, st1[r]);
        mx = fmaxf(mx, __shfl_xor(mx, 32));

        const float mnew = fmaxf(m2, mx * C2);
        const float cf = __builtin_exp2f(m2 - mnew);
        m2 = mnew;
        float rs = 0.f;
#pragma unroll
        for (int r = 0; r < 16; ++r) {
            st0[r] = __builtin_exp2f(fmaf(st0[r], C2, -m2));
            rs += st0[r];
        }
#pragma unroll
        for (int r = 0; r < 16; ++r) {
            st1[r] = __builtin_exp2f(fmaf(st1[r], C2, -m2));
            rs += st1[r];
        }
        rs += __shfl_xor(rs, 32);
        ll = ll * cf + rs;
#pragma unroll
        for (int r = 0; r < 16; ++r) { ot0[r] *= cf; ot1[r] *= cf; }

        // ---- P -> bf16 in registers: pack + cross-half exchange ----
        unsigned int pk0[8], pk1[8], x0[8], x1[8];
#pragma unroll
        for (int i = 0; i < 8; ++i) {
            pk0[i] = cvtpk(st0[2 * i], st0[2 * i + 1]);
            pk1[i] = cvtpk(st1[2 * i], st1[2 * i + 1]);
        }
#pragma unroll
        for (int i = 0; i < 8; ++i) {
            x0[i] = (unsigned int)__shfl_xor((int)pk0[i], 32);
            x1[i] = (unsigned int)__shfl_xor((int)pk1[i], 32);
        }
        // B-frags: tile0 keys 0-15 / 16-31, tile1 keys 32-47 / 48-63
        u32x4 pf[4];
        pf[0].x = hihalf ? x0[2] : pk0[0];  pf[0].y = hihalf ? x0[3] : pk0[1];
        pf[0].z = hihalf ? pk0[2] : x0[0];  pf[0].w = hihalf ? pk0[3] : x0[1];
        pf[1].x = hihalf ? x0[6] : pk0[4];  pf[1].y = hihalf ? x0[7] : pk0[5];
        pf[1].z = hihalf ? pk0[6] : x0[4];  pf[1].w = hihalf ? pk0[7] : x0[5];
        pf[2].x = hihalf ? x1[2] : pk1[0];  pf[2].y = hihalf ? x1[3] : pk1[1];
        pf[2].z = hihalf ? pk1[2] : x1[0];  pf[2].w = hihalf ? pk1[3] : x1[1];
        pf[3].x = hihalf ? x1[6] : pk1[4];  pf[3].y = hihalf ? x1[7] : pk1[5];
        pf[3].z = hihalf ? pk1[6] : x1[4];  pf[3].w = hihalf ? pk1[7] : x1[5];

        // ---- O^T += V^T·P^T : 2 d-tiles × 4 key-steps ----
#pragma unroll
        for (int ks2 = 0; ks2 < 4; ++ks2) {
            const short8v pfr = u2s(pf[ks2]);
            const int keyoff = ks2 * 16 + lh * 8;
            short8v vf0 = *(const short8v*)&Vt[(l31 * 64 + keyoff) ^ swr];
            ot0 = __builtin_amdgcn_mfma_f32_32x32x16_bf16(vf0, pfr, ot0, 0, 0, 0);
            short8v vf1 = *(const short8v*)&Vt[((32 + l31) * 64 + keyoff) ^ swr];
            ot1 = __builtin_amdgcn_mfma_f32_32x32x16_bf16(vf1, pfr, ot1, 0, 0, 0);
        }
    }

    // ---- finalize: lane holds q = l31; O^T rows are dims ----
    const float il = 1.0f / ll;
    const int qrow = qrow0 + l31;
    unsigned short* dh = aoh + (size_t)qrow * D_MODEL + h * 64;
    unsigned short* dl = aol + (size_t)qrow * D_MODEL + h * 64;
#pragma unroll
    for (int r = 0; r < 16; ++r) {
        const int dloc = (r & 3) + 8 * (r >> 2) + 4 * lh;
        unsigned short hh, lo2;
        split_bf(ot0[r] * il, hh, lo2);
        dh[dloc] = hh; dl[dloc] = lo2;
        split_bf(ot1[r] * il, hh, lo2);
        dh[32 + dloc] = hh; dl[32 + dloc] = lo2;
    }
}

// ---------------------------------------------------------------------------
extern "C" void kernel_launch(void* const* d_in, const int* in_sizes, int n_in,
                              void* d_out, int out_size, void* d_ws, size_t ws_size,
                              hipStream_t stream) {
    (void)in_sizes; (void)n_in; (void)out_size; (void)ws_size;

    const float* x     = (const float*)d_in[0];
    const float* w_qkv = (const float*)d_in[1];
    const float* b_qkv = (const float*)d_in[2];
    const float* w_out = (const float*)d_in[3];
    const float* b_out = (const float*)d_in[4];
    float* out = (float*)d_out;

    char* ws = (char*)d_ws;
    unsigned short* qkv_bf  = (unsigned short*)(ws);                       // 25,165,824 B
    unsigned short* aoh     = (unsigned short*)(ws + 25165824);            //  8,388,608 B
    unsigned short* aol     = (unsigned short*)(ws + 33554432);            //  8,388,608 B
    unsigned short* wqkvT_h = (unsigned short*)(ws + 41943040);            //  6,291,456 B
    unsigned short* wqkvT_l = (unsigned short*)(ws + 48234496);            //  6,291,456 B
    unsigned short* woutT_h = (unsigned short*)(ws + 54525952);            //  2,097,152 B
    unsigned short* woutT_l = (unsigned short*)(ws + 56623104);            //  2,097,152 B

    splitT_kernel<<<dim3((D_MODEL / 64) * (3 * D_MODEL / 64)), 256, 0, stream>>>(
        w_qkv, wqkvT_h, wqkvT_l, D_MODEL, 3 * D_MODEL);
    splitT_kernel<<<dim3((D_MODEL / 64) * (D_MODEL / 64)), 256, 0, stream>>>(
        w_out, woutT_h, woutT_l, D_MODEL, D_MODEL);

    gemm_xw_kernel<<<dim3((NROWS / 128) * (3 * D_MODEL / 128)), 256, 0, stream>>>(
        x, wqkvT_h, wqkvT_l, b_qkv, qkv_bf, NROWS, 3 * D_MODEL, D_MODEL);

    attn_mfma_kernel<<<dim3(NBATCH * N_HEADS, SEQ / 64), 128, 0, stream>>>(qkv_bf, aoh, aol);

    gemm_ao_kernel<<<dim3((NROWS / 128) * (D_MODEL / 128)), 256, 0, stream>>>(
        aoh, aol, woutT_h, woutT_l, b_out, out, NROWS, D_MODEL, D_MODEL);
}

// Round 6
// 213.403 us; speedup vs baseline: 7.6038x; 1.0002x over previous
//
#include <hip/hip_runtime.h>
#include <hip/hip_bf16.h>
#include <math.h>

#define D_MODEL 1024
#define N_HEADS 16
#define D_HEAD  64
#define SEQ     2048
#define NBATCH  2
#define NROWS   (NBATCH * SEQ)      // 4096

typedef __attribute__((ext_vector_type(8))) short short8v;        // 8 bf16
typedef __attribute__((ext_vector_type(4))) float f32x4;
typedef __attribute__((ext_vector_type(16))) float f32x16;
typedef __attribute__((ext_vector_type(4))) unsigned int u32x4;

__device__ __forceinline__ unsigned short f2bf(float x) {
    unsigned int u = __float_as_uint(x);
    return (unsigned short)((u + 0x7FFFu + ((u >> 16) & 1u)) >> 16);   // RNE
}
// truncation split: hi = top-16-bits of fp32, lo = RNE(x - hi)
__device__ __forceinline__ void split_bf(float x, unsigned short& hi, unsigned short& lo) {
    unsigned int u = __float_as_uint(x);
    unsigned int ht = u & 0xFFFF0000u;
    hi = (unsigned short)(ht >> 16);
    lo = f2bf(x - __uint_as_float(ht));
}
// packed RNE f32x2 -> bf16x2 (low16 = first arg, high16 = second arg)
__device__ __forceinline__ unsigned int cvtpk(float lo, float hi) {
    unsigned int r;
    asm("v_cvt_pk_bf16_f32 %0, %1, %2" : "=v"(r) : "v"(lo), "v"(hi));
    return r;
}
__device__ __forceinline__ short8v u2s(u32x4 v) {
    union { u32x4 u; short8v s; } c; c.u = v; return c.s;
}

// ---------------------------------------------------------------------------
// Weight transpose + split: W[K][N] fp32 -> Th[N][K], Tl[N][K] bf16
// ---------------------------------------------------------------------------
__global__ __launch_bounds__(256) void splitT_kernel(
    const float* __restrict__ W, unsigned short* __restrict__ Th,
    unsigned short* __restrict__ Tl, int K, int N)
{
    __shared__ float tile[64][68];
    const int tid = threadIdx.x;
    const int nbn = N >> 6;
    const int k0 = (blockIdx.x / nbn) << 6;
    const int n0 = (blockIdx.x % nbn) << 6;
    const int r  = tid >> 4;
    const int c4 = (tid & 15) * 4;

#pragma unroll
    for (int i = 0; i < 4; ++i) {
        float4 v = *(const float4*)(W + (size_t)(k0 + r + i * 16) * N + n0 + c4);
        *(float4*)&tile[r + i * 16][c4] = v;
    }
    __syncthreads();

    const int kl = (tid & 15) * 4;
#pragma unroll
    for (int i = 0; i < 4; ++i) {
        const int nl = (tid >> 4) + i * 16;
        ushort4 h4, l4;
        unsigned short h, l;
        split_bf(tile[kl + 0][nl], h, l); h4.x = h; l4.x = l;
        split_bf(tile[kl + 1][nl], h, l); h4.y = h; l4.y = l;
        split_bf(tile[kl + 2][nl], h, l); h4.z = h; l4.z = l;
        split_bf(tile[kl + 3][nl], h, l); h4.w = h; l4.w = l;
        *(ushort4*)(Th + (size_t)(n0 + nl) * K + k0 + kl) = h4;
        *(ushort4*)(Tl + (size_t)(n0 + nl) * K + k0 + kl) = l4;
    }
}

// ---------------------------------------------------------------------------
// GEMM1: qkv[M,N](bf16) = RNE_bf16(A[M,K] fp32) @ (Bh+Bl)[N,K]^T + bias
// ---------------------------------------------------------------------------
#define ASTRIDE 40    // bf16 elems; 80B row stride

__global__ __launch_bounds__(256) void gemm_xw_kernel(
    const float* __restrict__ A,
    const unsigned short* __restrict__ Bth,
    const unsigned short* __restrict__ Btl,
    const float* __restrict__ bias,
    unsigned short* __restrict__ C, int M, int N, int K)
{
    __shared__ __align__(16) unsigned short Ab[128][ASTRIDE];
    __shared__ __align__(16) unsigned short Bh[128][ASTRIDE];
    __shared__ __align__(16) unsigned short Bl[128][ASTRIDE];

    const int tid  = threadIdx.x;
    const int wave = tid >> 6;
    const int lane = tid & 63;
    const int col  = lane & 15;
    const int q4   = lane >> 4;
    const int wm   = (wave >> 1) * 64;
    const int wn   = (wave & 1) * 64;

    const int nwg = gridDim.x;
    const int cpx = nwg >> 3;
    const int swz = (blockIdx.x & 7) * cpx + (blockIdx.x >> 3);
    const int nbn = N / 128;
    const int bm = (swz / nbn) * 128;
    const int bn = (swz % nbn) * 128;

    const int sr = tid >> 1;
    const int sq = (tid & 1) * 16;
    const float* aptr = A + (size_t)(bm + sr) * K + sq;
    const unsigned short* bhp = Bth + (size_t)(bn + sr) * K + sq;
    const unsigned short* blp = Btl + (size_t)(bn + sr) * K + sq;

    f32x4 acc[4][4];
#pragma unroll
    for (int i = 0; i < 4; ++i)
#pragma unroll
        for (int j = 0; j < 4; ++j) acc[i][j] = (f32x4){0.f, 0.f, 0.f, 0.f};

    for (int k0 = 0; k0 < K; k0 += 32) {
        float4 a0 = *(const float4*)(aptr + k0);
        float4 a1 = *(const float4*)(aptr + k0 + 4);
        float4 a2 = *(const float4*)(aptr + k0 + 8);
        float4 a3 = *(const float4*)(aptr + k0 + 12);
        short8v b0h = *(const short8v*)(bhp + k0);
        short8v b1h = *(const short8v*)(bhp + k0 + 8);
        short8v b0l = *(const short8v*)(blp + k0);
        short8v b1l = *(const short8v*)(blp + k0 + 8);

        __syncthreads();
        {
            u32x4 p0, p1;
            p0.x = cvtpk(a0.x, a0.y); p0.y = cvtpk(a0.z, a0.w);
            p0.z = cvtpk(a1.x, a1.y); p0.w = cvtpk(a1.z, a1.w);
            p1.x = cvtpk(a2.x, a2.y); p1.y = cvtpk(a2.z, a2.w);
            p1.z = cvtpk(a3.x, a3.y); p1.w = cvtpk(a3.z, a3.w);
            *(u32x4*)&Ab[sr][sq]     = p0;
            *(u32x4*)&Ab[sr][sq + 8] = p1;
            *(short8v*)&Bh[sr][sq]     = b0h;
            *(short8v*)&Bh[sr][sq + 8] = b1h;
            *(short8v*)&Bl[sr][sq]     = b0l;
            *(short8v*)&Bl[sr][sq + 8] = b1l;
        }
        __syncthreads();

        short8v af[4];
#pragma unroll
        for (int mt = 0; mt < 4; ++mt)
            af[mt] = *(const short8v*)&Ab[wm + mt * 16 + col][q4 * 8];
#pragma unroll
        for (int nt = 0; nt < 4; ++nt) {
            short8v bhf = *(const short8v*)&Bh[wn + nt * 16 + col][q4 * 8];
            short8v blf = *(const short8v*)&Bl[wn + nt * 16 + col][q4 * 8];
#pragma unroll
            for (int mt = 0; mt < 4; ++mt) {
                acc[mt][nt] = __builtin_amdgcn_mfma_f32_16x16x32_bf16(af[mt], bhf, acc[mt][nt], 0, 0, 0);
                acc[mt][nt] = __builtin_amdgcn_mfma_f32_16x16x32_bf16(af[mt], blf, acc[mt][nt], 0, 0, 0);
            }
        }
    }

    float bv[4];
#pragma unroll
    for (int nt = 0; nt < 4; ++nt) bv[nt] = bias[bn + wn + nt * 16 + col];

#pragma unroll
    for (int mt = 0; mt < 4; ++mt)
#pragma unroll
        for (int r = 0; r < 4; ++r) {
            const int row = bm + wm + mt * 16 + q4 * 4 + r;
#pragma unroll
            for (int nt = 0; nt < 4; ++nt)
                C[(size_t)row * N + bn + wn + nt * 16 + col] = f2bf(acc[mt][nt][r] + bv[nt]);
        }
}

// ---------------------------------------------------------------------------
// GEMM2: out[M,N](fp32) = (Aoh+Aol)[M,K] @ (Bh+Bl)[N,K]^T + bias, 3-term.
// ---------------------------------------------------------------------------
__global__ __launch_bounds__(256) void gemm_ao_kernel(
    const unsigned short* __restrict__ Aoh,
    const unsigned short* __restrict__ Aol,
    const unsigned short* __restrict__ Bth,
    const unsigned short* __restrict__ Btl,
    const float* __restrict__ bias,
    float* __restrict__ C, int M, int N, int K)
{
    __shared__ __align__(16) unsigned short Ah[128][ASTRIDE];
    __shared__ __align__(16) unsigned short Al[128][ASTRIDE];
    __shared__ __align__(16) unsigned short Bh[128][ASTRIDE];
    __shared__ __align__(16) unsigned short Bl[128][ASTRIDE];

    const int tid  = threadIdx.x;
    const int wave = tid >> 6;
    const int lane = tid & 63;
    const int col  = lane & 15;
    const int q4   = lane >> 4;
    const int wm   = (wave >> 1) * 64;
    const int wn   = (wave & 1) * 64;

    const int nwg = gridDim.x;
    const int cpx = nwg >> 3;
    const int swz = (blockIdx.x & 7) * cpx + (blockIdx.x >> 3);
    const int nbn = N / 128;
    const int bm = (swz / nbn) * 128;
    const int bn = (swz % nbn) * 128;

    const int sr = tid >> 1;
    const int sq = (tid & 1) * 16;
    const unsigned short* ahp = Aoh + (size_t)(bm + sr) * K + sq;
    const unsigned short* alp = Aol + (size_t)(bm + sr) * K + sq;
    const unsigned short* bhp = Bth + (size_t)(bn + sr) * K + sq;
    const unsigned short* blp = Btl + (size_t)(bn + sr) * K + sq;

    f32x4 acc[4][4];
#pragma unroll
    for (int i = 0; i < 4; ++i)
#pragma unroll
        for (int j = 0; j < 4; ++j) acc[i][j] = (f32x4){0.f, 0.f, 0.f, 0.f};

    for (int k0 = 0; k0 < K; k0 += 32) {
        short8v a0h = *(const short8v*)(ahp + k0);
        short8v a1h = *(const short8v*)(ahp + k0 + 8);
        short8v a0l = *(const short8v*)(alp + k0);
        short8v a1l = *(const short8v*)(alp + k0 + 8);
        short8v b0h = *(const short8v*)(bhp + k0);
        short8v b1h = *(const short8v*)(bhp + k0 + 8);
        short8v b0l = *(const short8v*)(blp + k0);
        short8v b1l = *(const short8v*)(blp + k0 + 8);

        __syncthreads();
        *(short8v*)&Ah[sr][sq]     = a0h;
        *(short8v*)&Ah[sr][sq + 8] = a1h;
        *(short8v*)&Al[sr][sq]     = a0l;
        *(short8v*)&Al[sr][sq + 8] = a1l;
        *(short8v*)&Bh[sr][sq]     = b0h;
        *(short8v*)&Bh[sr][sq + 8] = b1h;
        *(short8v*)&Bl[sr][sq]     = b0l;
        *(short8v*)&Bl[sr][sq + 8] = b1l;
        __syncthreads();

        short8v ahf[4], alf[4];
#pragma unroll
        for (int mt = 0; mt < 4; ++mt) {
            ahf[mt] = *(const short8v*)&Ah[wm + mt * 16 + col][q4 * 8];
            alf[mt] = *(const short8v*)&Al[wm + mt * 16 + col][q4 * 8];
        }
#pragma unroll
        for (int nt = 0; nt < 4; ++nt) {
            short8v bhf = *(const short8v*)&Bh[wn + nt * 16 + col][q4 * 8];
            short8v blf = *(const short8v*)&Bl[wn + nt * 16 + col][q4 * 8];
#pragma unroll
            for (int mt = 0; mt < 4; ++mt) {
                acc[mt][nt] = __builtin_amdgcn_mfma_f32_16x16x32_bf16(ahf[mt], bhf, acc[mt][nt], 0, 0, 0);
                acc[mt][nt] = __builtin_amdgcn_mfma_f32_16x16x32_bf16(alf[mt], bhf, acc[mt][nt], 0, 0, 0);
                acc[mt][nt] = __builtin_amdgcn_mfma_f32_16x16x32_bf16(ahf[mt], blf, acc[mt][nt], 0, 0, 0);
            }
        }
    }

    float bv[4];
#pragma unroll
    for (int nt = 0; nt < 4; ++nt) bv[nt] = bias[bn + wn + nt * 16 + col];

#pragma unroll
    for (int mt = 0; mt < 4; ++mt)
#pragma unroll
        for (int r = 0; r < 4; ++r) {
            const int row = bm + wm + mt * 16 + q4 * 4 + r;
#pragma unroll
            for (int nt = 0; nt < 4; ++nt)
                C[(size_t)row * N + bn + wn + nt * 16 + col] = acc[mt][nt][r] + bv[nt];
        }
}

// ---------------------------------------------------------------------------
// MFMA flash attention, transposed-space 32x32x16, in-block K-split.
// Block: 256 threads = 4 waves. wave = qhalf(bit0) x khalf(bit1).
// Wave handles 32 q-rows over its 1024-key half; dual 64-key LDS chunks.
// S^T = K·Q^T (lane = q-col, full row in regs); in-lane softmax + 1 shfl;
// P packed to bf16 in regs; O^T = V^T·P^T. Defer-max (THR=8 in log2 units).
// End: cross-wave merge of the two k-half partials via LDS (reused buffers).
// LDS: 32 KB. Grid 1024 blocks x 4 waves = 16 waves/CU.
// ---------------------------------------------------------------------------
__global__ __launch_bounds__(256) void attn_mfma_kernel(
    const unsigned short* __restrict__ qkv,
    unsigned short* __restrict__ aoh, unsigned short* __restrict__ aol)
{
    __shared__ __align__(16) unsigned short Ks[2][64 * 64];   // [chunk][key][dim] swizzled
    __shared__ __align__(16) unsigned short Vt[2][64 * 64];   // [chunk][dim][key] swizzled

    const int tid  = threadIdx.x;
    const int wave = tid >> 6;           // 0..3
    const int lane = tid & 63;
    const int l31  = lane & 31;
    const int lh   = lane >> 5;          // 0 or 1
    const bool hihalf = (lh != 0);
    const int qhalf = wave & 1;          // which 32 q-rows
    const int khalf = wave >> 1;         // which 1024-key half

    const int bh = blockIdx.x;           // b*16 + h
    const int qt = blockIdx.y;           // 0..31
    const int b = bh >> 4;
    const int h = bh & 15;
    const int qrow0 = b * SEQ + qt * 64 + qhalf * 32;
    const int krow0 = b * SEQ + khalf * 1024;   // this wave's key base
    const int krow0s = b * SEQ;                 // staging base (covers both halves)

    // Q fragments (B-operand): qf[s][j] = Q[qrow0+l31][s*16 + lh*8 + j]
    short8v qf[4];
    {
        const unsigned short* qsrc = qkv + (size_t)(qrow0 + l31) * (3 * D_MODEL) + h * 64 + lh * 8;
#pragma unroll
        for (int s = 0; s < 4; ++s)
            qf[s] = *(const short8v*)(qsrc + s * 16);
    }

    // staging indices (256 threads stage 128 key-rows: chunk0 @ +0, chunk1 @ +1024)
    const int skr = tid >> 1;            // 0..127
    const int skc = skr >> 6;            // chunk 0/1
    const int skk = skr & 63;            // key within chunk
    const int skh = (tid & 1) * 32;      // elem offset (half row)
    const int vkr = (tid & 31) * 4;      // 0..124
    const int vkc = vkr >> 6;            // chunk 0/1
    const int vkk = vkr & 63;            // key within chunk
    const int vd0 = (tid >> 5) * 8;      // 0..56

    f32x16 ot0, ot1;
#pragma unroll
    for (int r = 0; r < 16; ++r) { ot0[r] = 0.f; ot1[r] = 0.f; }
    float m2 = -1e30f, ll = 0.f;
    const float C2 = 0.18033688011112042f;   // 0.125 * log2(e)

    for (int i = 0; i < 16; ++i) {
        const int kc = i * 64;
        // ---- global loads ----
        const unsigned short* ksrc = qkv + (size_t)(krow0s + skc * 1024 + kc + skk) * (3 * D_MODEL)
                                     + D_MODEL + h * 64 + skh;
        short8v kg0 = ((const short8v*)ksrc)[0];
        short8v kg1 = ((const short8v*)ksrc)[1];
        short8v kg2 = ((const short8v*)ksrc)[2];
        short8v kg3 = ((const short8v*)ksrc)[3];
        short8v vg[4];
#pragma unroll
        for (int j = 0; j < 4; ++j)
            vg[j] = *(const short8v*)(qkv + (size_t)(krow0s + vkc * 1024 + kc + vkk + j) * (3 * D_MODEL)
                                      + 2 * D_MODEL + h * 64 + vd0);

        __syncthreads();   // prev chunk's LDS reads done

        // K row-major, swizzled
        {
            const int base = skk * 64 + skh;
            const int sw = (skk & 7) << 3;
            unsigned short* kd = &Ks[skc][0];
            *(short8v*)&kd[(base)      ^ sw] = kg0;
            *(short8v*)&kd[(base + 8)  ^ sw] = kg1;
            *(short8v*)&kd[(base + 16) ^ sw] = kg2;
            *(short8v*)&kd[(base + 24) ^ sw] = kg3;
        }
        // V transposed: Vt[dim][key], swizzled
#pragma unroll
        for (int jd = 0; jd < 8; ++jd) {
            ushort4 w;
            w.x = ((const unsigned short*)&vg[0])[jd];
            w.y = ((const unsigned short*)&vg[1])[jd];
            w.z = ((const unsigned short*)&vg[2])[jd];
            w.w = ((const unsigned short*)&vg[3])[jd];
            const int d = vd0 + jd;
            *(ushort4*)&Vt[vkc][(d * 64 + vkk) ^ ((d & 7) << 3)] = w;
        }
        __syncthreads();

        // ---- S^T = K·Q^T : 2 key-tiles x 4 d-steps ----
        f32x16 st0, st1;
#pragma unroll
        for (int r = 0; r < 16; ++r) { st0[r] = 0.f; st1[r] = 0.f; }
        const int swr = (lane & 7) << 3;
        const unsigned short* kbuf = &Ks[khalf][0];
        const unsigned short* vbuf = &Vt[khalf][0];
#pragma unroll
        for (int s = 0; s < 4; ++s) {
            short8v kf0 = *(const short8v*)&kbuf[(l31 * 64 + s * 16 + lh * 8) ^ swr];
            st0 = __builtin_amdgcn_mfma_f32_32x32x16_bf16(kf0, qf[s], st0, 0, 0, 0);
        }
#pragma unroll
        for (int s = 0; s < 4; ++s) {
            short8v kf1 = *(const short8v*)&kbuf[((32 + l31) * 64 + s * 16 + lh * 8) ^ swr];
            st1 = __builtin_amdgcn_mfma_f32_32x32x16_bf16(kf1, qf[s], st1, 0, 0, 0);
        }

        // ---- in-lane online softmax with defer-max ----
        float mx = st0[0];
#pragma unroll
        for (int r = 1; r < 16; ++r) mx = fmaxf(mx, st0[r]);
#pragma unroll
        for (int r = 0; r < 16; ++r) mx = fmaxf(mx, st1[r]);
        mx = fmaxf(mx, __shfl_xor(mx, 32));
        const float mxl = mx * C2;

        if (__any(mxl > m2 + 8.0f)) {
            const float mnew = fmaxf(m2, mxl);
            const float cf = __builtin_exp2f(m2 - mnew);
            m2 = mnew;
            ll *= cf;
#pragma unroll
            for (int r = 0; r < 16; ++r) { ot0[r] *= cf; ot1[r] *= cf; }
        }

        float rs = 0.f;
#pragma unroll
        for (int r = 0; r < 16; ++r) {
            st0[r] = __builtin_exp2f(fmaf(st0[r], C2, -m2));
            rs += st0[r];
        }
#pragma unroll
        for (int r = 0; r < 16; ++r) {
            st1[r] = __builtin_exp2f(fmaf(st1[r], C2, -m2));
            rs += st1[r];
        }
        rs += __shfl_xor(rs, 32);
        ll += rs;

        // ---- P -> bf16 in registers: pack + cross-half exchange ----
        unsigned int pk0[8], pk1[8], x0[8], x1[8];
#pragma unroll
        for (int j = 0; j < 8; ++j) {
            pk0[j] = cvtpk(st0[2 * j], st0[2 * j + 1]);
            pk1[j] = cvtpk(st1[2 * j], st1[2 * j + 1]);
        }
#pragma unroll
        for (int j = 0; j < 8; ++j) {
            x0[j] = (unsigned int)__shfl_xor((int)pk0[j], 32);
            x1[j] = (unsigned int)__shfl_xor((int)pk1[j], 32);
        }
        u32x4 pf[4];
        pf[0].x = hihalf ? x0[2] : pk0[0];  pf[0].y = hihalf ? x0[3] : pk0[1];
        pf[0].z = hihalf ? pk0[2] : x0[0];  pf[0].w = hihalf ? pk0[3] : x0[1];
        pf[1].x = hihalf ? x0[6] : pk0[4];  pf[1].y = hihalf ? x0[7] : pk0[5];
        pf[1].z = hihalf ? pk0[6] : x0[4];  pf[1].w = hihalf ? pk0[7] : x0[5];
        pf[2].x = hihalf ? x1[2] : pk1[0];  pf[2].y = hihalf ? x1[3] : pk1[1];
        pf[2].z = hihalf ? pk1[2] : x1[0];  pf[2].w = hihalf ? pk1[3] : x1[1];
        pf[3].x = hihalf ? x1[6] : pk1[4];  pf[3].y = hihalf ? x1[7] : pk1[5];
        pf[3].z = hihalf ? pk1[6] : x1[4];  pf[3].w = hihalf ? pk1[7] : x1[5];

        // ---- O^T += V^T·P^T : 2 d-tiles x 4 key-steps ----
#pragma unroll
        for (int ks2 = 0; ks2 < 4; ++ks2) {
            const short8v pfr = u2s(pf[ks2]);
            const int keyoff = ks2 * 16 + lh * 8;
            short8v vf0 = *(const short8v*)&vbuf[(l31 * 64 + keyoff) ^ swr];
            ot0 = __builtin_amdgcn_mfma_f32_32x32x16_bf16(vf0, pfr, ot0, 0, 0, 0);
            short8v vf1 = *(const short8v*)&vbuf[((32 + l31) * 64 + keyoff) ^ swr];
            ot1 = __builtin_amdgcn_mfma_f32_32x32x16_bf16(vf1, pfr, ot1, 0, 0, 0);
        }
    }

    // ---- cross-wave merge of k-half partials (LDS reuse) ----
    float* xf  = (float*)&Ks[0][0];   // 4096 floats = 16 KB
    float* xml = (float*)&Vt[0][0];   // m,l exchange

    __syncthreads();
    if (wave >= 2) {
        const int reg = (wave & 1) * 2048;
#pragma unroll
        for (int r = 0; r < 16; ++r) xf[reg + r * 64 + lane] = ot0[r];
#pragma unroll
        for (int r = 0; r < 16; ++r) xf[reg + (16 + r) * 64 + lane] = ot1[r];
        xml[(wave & 1) * 128 + lane] = m2;
        xml[(wave & 1) * 128 + 64 + lane] = ll;
    }
    __syncthreads();
    if (wave < 2) {
        const int reg = wave * 2048;
        const float m2b = xml[wave * 128 + lane];
        const float llb = xml[wave * 128 + 64 + lane];
        const float M  = fmaxf(m2, m2b);
        const float ca = __builtin_exp2f(m2 - M);
        const float cb = __builtin_exp2f(m2b - M);
        const float il = 1.0f / (ll * ca + llb * cb);

        const int qrow = qrow0 + l31;
        unsigned short* dh = aoh + (size_t)qrow * D_MODEL + h * 64;
        unsigned short* dl = aol + (size_t)qrow * D_MODEL + h * 64;
#pragma unroll
        for (int r = 0; r < 16; ++r) {
            const int dloc = (r & 3) + 8 * (r >> 2) + 4 * lh;
            unsigned short hh, lo2;
            split_bf((ot0[r] * ca + xf[reg + r * 64 + lane] * cb) * il, hh, lo2);
            dh[dloc] = hh; dl[dloc] = lo2;
            split_bf((ot1[r] * ca + xf[reg + (16 + r) * 64 + lane] * cb) * il, hh, lo2);
            dh[32 + dloc] = hh; dl[32 + dloc] = lo2;
        }
    }
}

// ---------------------------------------------------------------------------
extern "C" void kernel_launch(void* const* d_in, const int* in_sizes, int n_in,
                              void* d_out, int out_size, void* d_ws, size_t ws_size,
                              hipStream_t stream) {
    (void)in_sizes; (void)n_in; (void)out_size; (void)ws_size;

    const float* x     = (const float*)d_in[0];
    const float* w_qkv = (const float*)d_in[1];
    const float* b_qkv = (const float*)d_in[2];
    const float* w_out = (const float*)d_in[3];
    const float* b_out = (const float*)d_in[4];
    float* out = (float*)d_out;

    char* ws = (char*)d_ws;
    unsigned short* qkv_bf  = (unsigned short*)(ws);                       // 25,165,824 B
    unsigned short* aoh     = (unsigned short*)(ws + 25165824);            //  8,388,608 B
    unsigned short* aol     = (unsigned short*)(ws + 33554432);            //  8,388,608 B
    unsigned short* wqkvT_h = (unsigned short*)(ws + 41943040);            //  6,291,456 B
    unsigned short* wqkvT_l = (unsigned short*)(ws + 48234496);            //  6,291,456 B
    unsigned short* woutT_h = (unsigned short*)(ws + 54525952);            //  2,097,152 B
    unsigned short* woutT_l = (unsigned short*)(ws + 56623104);            //  2,097,152 B

    splitT_kernel<<<dim3((D_MODEL / 64) * (3 * D_MODEL / 64)), 256, 0, stream>>>(
        w_qkv, wqkvT_h, wqkvT_l, D_MODEL, 3 * D_MODEL);
    splitT_kernel<<<dim3((D_MODEL / 64) * (D_MODEL / 64)), 256, 0, stream>>>(
        w_out, woutT_h, woutT_l, D_MODEL, D_MODEL);

    gemm_xw_kernel<<<dim3((NROWS / 128) * (3 * D_MODEL / 128)), 256, 0, stream>>>(
        x, wqkvT_h, wqkvT_l, b_qkv, qkv_bf, NROWS, 3 * D_MODEL, D_MODEL);

    attn_mfma_kernel<<<dim3(NBATCH * N_HEADS, SEQ / 64), 256, 0, stream>>>(qkv_bf, aoh, aol);

    gemm_ao_kernel<<<dim3((NROWS / 128) * (D_MODEL / 128)), 256, 0, stream>>>(
        aoh, aol, woutT_h, woutT_l, b_out, out, NROWS, D_MODEL, D_MODEL);
}